// Round 1
// baseline (1676.176 us; speedup 1.0000x reference)
//
#include <hip/hip_runtime.h>

#define B_ 256
#define C_ 64
#define L_ 512
#define CIN_ 82
#define NFREQ_ 9
#define EMB_ 256
#define NLAB_ 10
#define PT_ 37056
#define OFF_BH 16384
#define OFF_WL 16448
#define OFF_BL 20544
#define OFF_WS 20608
#define OFF_BS 36992
#define PI_F 3.14159265358979323846f

typedef short bh8 __attribute__((ext_vector_type(8)));   // 8 bf16 (raw bits)
typedef float f32x4 __attribute__((ext_vector_type(4)));

__device__ inline float lrelu(float v){ return v > 0.f ? v : 0.2f*v; }

__device__ inline unsigned short f2bf(float f){
  unsigned u = __float_as_uint(f);
  u += 0x7FFFu + ((u >> 16) & 1u);      // RNE
  return (unsigned short)(u >> 16);
}
__device__ inline unsigned pk2(float a, float b){
  return (unsigned)f2bf(a) | ((unsigned)f2bf(b) << 16);
}
__device__ inline bh8 cvt8(float4 a, float4 b){
  bh8 r;
  r[0]=(short)f2bf(a.x); r[1]=(short)f2bf(a.y); r[2]=(short)f2bf(a.z); r[3]=(short)f2bf(a.w);
  r[4]=(short)f2bf(b.x); r[5]=(short)f2bf(b.y); r[6]=(short)f2bf(b.z); r[7]=(short)f2bf(b.w);
  return r;
}

// ---------------- yemb: normalize(fc_w[:,y]+fc_b), store transposed [e][b]; zero loss slot
__global__ __launch_bounds__(256) void k_yemb(const float* __restrict__ fc_w,
    const float* __restrict__ fc_b, const int* __restrict__ y,
    float* __restrict__ yembT, float* __restrict__ out){
  int b = blockIdx.x, e = threadIdx.x;
  int lab = y[b];
  float v = fc_w[e*NLAB_ + lab] + fc_b[e];
  __shared__ float red[256];
  red[e] = v*v; __syncthreads();
  for (int s = 128; s; s >>= 1){ if (e < s) red[e] += red[e+s]; __syncthreads(); }
  float nrm = fmaxf(sqrtf(red[0]), 1e-12f);
  yembT[e*B_ + b] = v / nrm;
  if (b == 0 && e == 0) out[B_*L_] = 0.f;
}

// ---------------- hyper: p[b][j] = sum_e yemb[b][e]*hyper_w[j][e] + hyper_b[j]
// block = 16 j's; thread: 4 b's (bq=tid&63) x 4 j's (jg=tid>>6)
__global__ __launch_bounds__(256) void k_hyper(const float* __restrict__ hw,
    const float* __restrict__ hb, const float* __restrict__ yembT, float* __restrict__ p){
  int j0 = blockIdx.x * 16;
  int bq = threadIdx.x & 63;
  int jg = threadIdx.x >> 6;
  float acc[4][4];
  #pragma unroll
  for (int rb = 0; rb < 4; rb++)
    #pragma unroll
    for (int rj = 0; rj < 4; rj++) acc[rb][rj] = hb[j0 + jg*4 + rj];
  for (int e = 0; e < 256; e++){
    float4 yv = *(const float4*)&yembT[e*B_ + bq*4];
    float w[4];
    #pragma unroll
    for (int rj = 0; rj < 4; rj++) w[rj] = hw[(size_t)(j0 + jg*4 + rj)*EMB_ + e];
    #pragma unroll
    for (int rj = 0; rj < 4; rj++){
      acc[0][rj] += yv.x * w[rj];
      acc[1][rj] += yv.y * w[rj];
      acc[2][rj] += yv.z * w[rj];
      acc[3][rj] += yv.w * w[rj];
    }
  }
  #pragma unroll
  for (int rb = 0; rb < 4; rb++){
    float4 o = { acc[rb][0], acc[rb][1], acc[rb][2], acc[rb][3] };
    *(float4*)&p[(size_t)(bq*4 + rb)*PT_ + j0 + jg*4] = o;
  }
}

// positional encoding value (raw, no leaky)
__device__ inline float pe_raw(int fi, int l){
  if (fi < NFREQ_) return __sinf(PI_F / (float)(1 << fi) * (float)l);
  return __cosf(PI_F / (float)(1 << (fi - NFREQ_)) * (float)l);
}

// ---------------- conv_in1: t1 = conv3(leaky(xcat), in_w0) + in_b0
__global__ __launch_bounds__(512) void k_conv_in1(const float* __restrict__ codes,
    const float* __restrict__ w0, const float* __restrict__ b0, float* __restrict__ t1){
  int b = blockIdx.x, c0 = blockIdx.y * 8, l = threadIdx.x;
  float acc[8];
  #pragma unroll
  for (int j = 0; j < 8; j++) acc[j] = b0[c0+j];
  const float* cb = codes + (size_t)b*C_*L_;
  for (int i = 0; i < CIN_; i++){
    float x0, x1, x2;
    if (i < C_){
      const float* r = cb + i*L_ + l;
      x0 = (l > 0) ? r[-1] : 0.f; x1 = r[0]; x2 = (l < L_-1) ? r[1] : 0.f;
    } else {
      int fi = i - C_;
      x0 = (l > 0) ? pe_raw(fi, l-1) : 0.f;
      x1 = pe_raw(fi, l);
      x2 = (l < L_-1) ? pe_raw(fi, l+1) : 0.f;
    }
    x0 = lrelu(x0); x1 = lrelu(x1); x2 = lrelu(x2);
    const float* w = w0 + ((size_t)c0*CIN_ + i)*3;
    #pragma unroll
    for (int j = 0; j < 8; j++){
      const float* wj = w + (size_t)j*CIN_*3;
      acc[j] += wj[0]*x0 + wj[1]*x1 + wj[2]*x2;
    }
  }
  #pragma unroll
  for (int j = 0; j < 8; j++) t1[((size_t)b*C_ + c0 + j)*L_ + l] = acc[j];
}

// ---------------- conv_in2: x = conv1x1(xcat, in_ws) + 0.1*(conv3(leaky(t1), in_w1)+in_b1)
__global__ __launch_bounds__(512) void k_conv_in2(const float* __restrict__ codes,
    const float* __restrict__ wsw, const float* __restrict__ w1, const float* __restrict__ b1,
    const float* __restrict__ t1, float* __restrict__ x){
  int b = blockIdx.x, c0 = blockIdx.y * 8, l = threadIdx.x;
  float accA[8], accB[8];
  #pragma unroll
  for (int j = 0; j < 8; j++){ accA[j] = 0.f; accB[j] = 0.f; }
  const float* cb = codes + (size_t)b*C_*L_;
  for (int i = 0; i < CIN_; i++){
    float xv = (i < C_) ? cb[i*L_ + l] : pe_raw(i - C_, l);
    #pragma unroll
    for (int j = 0; j < 8; j++) accA[j] += wsw[(size_t)(c0+j)*CIN_ + i] * xv;
  }
  const float* tb = t1 + (size_t)b*C_*L_;
  for (int f = 0; f < C_; f++){
    const float* r = tb + f*L_ + l;
    float x0 = (l > 0) ? lrelu(r[-1]) : 0.f;
    float x1 = lrelu(r[0]);
    float x2 = (l < L_-1) ? lrelu(r[1]) : 0.f;
    const float* w = w1 + ((size_t)c0*C_ + f)*3;
    #pragma unroll
    for (int j = 0; j < 8; j++){
      const float* wj = w + (size_t)j*C_*3;
      accB[j] += wj[0]*x0 + wj[1]*x1 + wj[2]*x2;
    }
  }
  #pragma unroll
  for (int j = 0; j < 8; j++)
    x[((size_t)b*C_ + c0 + j)*L_ + l] = accA[j] + 0.1f*(b1[c0+j] + accB[j]);
}

// ---------------- feat: inst-norm + separable sin-sobel -> bf16 feat[b][256][512]
// wave per (b,c); lane = z*8+y, handles full x-row of 8
__global__ __launch_bounds__(256) void k_feat(const float* __restrict__ x,
    unsigned short* __restrict__ feat){
  int wid = threadIdx.x >> 6, lane = threadIdx.x & 63;
  int gi = blockIdx.x*4 + wid;                 // = b*64 + c
  const float* xr = x + (size_t)gi*L_ + lane*8;
  float4 v0 = *(const float4*)xr;
  float4 v1 = *(const float4*)(xr + 4);
  float r[8] = { v0.x, v0.y, v0.z, v0.w, v1.x, v1.y, v1.z, v1.w };
  float s1 = 0.f, s2 = 0.f;
  #pragma unroll
  for (int i = 0; i < 8; i++){ s1 += r[i]; s2 += r[i]*r[i]; }
  for (int m = 32; m; m >>= 1){ s1 += __shfl_xor(s1, m); s2 += __shfl_xor(s2, m); }
  float mean = s1 * (1.f/512.f);
  float rstd = rsqrtf(s2*(1.f/512.f) - mean*mean + 1e-5f);
  float xn[8];
  #pragma unroll
  for (int i = 0; i < 8; i++) xn[i] = (r[i] - mean) * rstd;

  size_t fb = ((size_t)(gi >> 6)*4*C_ + (gi & 63))*L_ + lane*8;  // b*256*512 + c*512 + lane*8
  { uint4 o = { pk2(xn[0],xn[1]), pk2(xn[2],xn[3]), pk2(xn[4],xn[5]), pk2(xn[6],xn[7]) };
    *(uint4*)(feat + fb) = o; }

  __shared__ float S[4][5][64][8];   // per-wave: A,B,C,D,E
  float A[8], Bv[8];
  A[0] = 2.f*xn[0] + xn[1];           Bv[0] = xn[1];
  #pragma unroll
  for (int i = 1; i < 7; i++){ A[i] = xn[i-1] + 2.f*xn[i] + xn[i+1]; Bv[i] = xn[i+1] - xn[i-1]; }
  A[7] = xn[6] + 2.f*xn[7];           Bv[7] = -xn[6];
  { float4 a0 = {A[0],A[1],A[2],A[3]}, a1 = {A[4],A[5],A[6],A[7]};
    float4 b0 = {Bv[0],Bv[1],Bv[2],Bv[3]}, b1 = {Bv[4],Bv[5],Bv[6],Bv[7]};
    *(float4*)&S[wid][0][lane][0] = a0; *(float4*)&S[wid][0][lane][4] = a1;
    *(float4*)&S[wid][1][lane][0] = b0; *(float4*)&S[wid][1][lane][4] = b1; }
  __syncthreads();

  int yy = lane & 7, zz = lane >> 3;
  int lm = (yy > 0) ? lane-1 : lane;  float wm = (yy > 0) ? 1.f : 0.f;
  int lp = (yy < 7) ? lane+1 : lane;  float wp = (yy < 7) ? 1.f : 0.f;
  float Am[8], Ap[8], Bm[8], Bp[8];
  { float4 u0, u1;
    u0 = *(const float4*)&S[wid][0][lm][0]; u1 = *(const float4*)&S[wid][0][lm][4];
    Am[0]=u0.x*wm; Am[1]=u0.y*wm; Am[2]=u0.z*wm; Am[3]=u0.w*wm; Am[4]=u1.x*wm; Am[5]=u1.y*wm; Am[6]=u1.z*wm; Am[7]=u1.w*wm;
    u0 = *(const float4*)&S[wid][0][lp][0]; u1 = *(const float4*)&S[wid][0][lp][4];
    Ap[0]=u0.x*wp; Ap[1]=u0.y*wp; Ap[2]=u0.z*wp; Ap[3]=u0.w*wp; Ap[4]=u1.x*wp; Ap[5]=u1.y*wp; Ap[6]=u1.z*wp; Ap[7]=u1.w*wp;
    u0 = *(const float4*)&S[wid][1][lm][0]; u1 = *(const float4*)&S[wid][1][lm][4];
    Bm[0]=u0.x*wm; Bm[1]=u0.y*wm; Bm[2]=u0.z*wm; Bm[3]=u0.w*wm; Bm[4]=u1.x*wm; Bm[5]=u1.y*wm; Bm[6]=u1.z*wm; Bm[7]=u1.w*wm;
    u0 = *(const float4*)&S[wid][1][lp][0]; u1 = *(const float4*)&S[wid][1][lp][4];
    Bp[0]=u0.x*wp; Bp[1]=u0.y*wp; Bp[2]=u0.z*wp; Bp[3]=u0.w*wp; Bp[4]=u1.x*wp; Bp[5]=u1.y*wp; Bp[6]=u1.z*wp; Bp[7]=u1.w*wp;
  }
  float Cv[8], Dv[8], Ev[8];
  #pragma unroll
  for (int i = 0; i < 8; i++){
    Cv[i] = Am[i] + 2.f*A[i] + Ap[i];
    Dv[i] = Ap[i] - Am[i];
    Ev[i] = Bm[i] + 2.f*Bv[i] + Bp[i];
  }
  { float4 c0={Cv[0],Cv[1],Cv[2],Cv[3]}, c1={Cv[4],Cv[5],Cv[6],Cv[7]};
    float4 d0={Dv[0],Dv[1],Dv[2],Dv[3]}, d1={Dv[4],Dv[5],Dv[6],Dv[7]};
    float4 e0={Ev[0],Ev[1],Ev[2],Ev[3]}, e1={Ev[4],Ev[5],Ev[6],Ev[7]};
    *(float4*)&S[wid][2][lane][0]=c0; *(float4*)&S[wid][2][lane][4]=c1;
    *(float4*)&S[wid][3][lane][0]=d0; *(float4*)&S[wid][3][lane][4]=d1;
    *(float4*)&S[wid][4][lane][0]=e0; *(float4*)&S[wid][4][lane][4]=e1; }
  __syncthreads();

  int zm = (zz > 0) ? lane-8 : lane;  float qm = (zz > 0) ? 1.f : 0.f;
  int zp = (zz < 7) ? lane+8 : lane;  float qp = (zz < 7) ? 1.f : 0.f;
  float g0[8], g1[8], g2[8];
  { float4 u0, u1, w0, w1;
    // C at z-1 / z+1
    u0 = *(const float4*)&S[wid][2][zm][0]; u1 = *(const float4*)&S[wid][2][zm][4];
    w0 = *(const float4*)&S[wid][2][zp][0]; w1 = *(const float4*)&S[wid][2][zp][4];
    g0[0]=w0.x*qp-u0.x*qm; g0[1]=w0.y*qp-u0.y*qm; g0[2]=w0.z*qp-u0.z*qm; g0[3]=w0.w*qp-u0.w*qm;
    g0[4]=w1.x*qp-u1.x*qm; g0[5]=w1.y*qp-u1.y*qm; g0[6]=w1.z*qp-u1.z*qm; g0[7]=w1.w*qp-u1.w*qm;
    // D: s_z
    u0 = *(const float4*)&S[wid][3][zm][0]; u1 = *(const float4*)&S[wid][3][zm][4];
    w0 = *(const float4*)&S[wid][3][zp][0]; w1 = *(const float4*)&S[wid][3][zp][4];
    g1[0]=u0.x*qm+2.f*Dv[0]+w0.x*qp; g1[1]=u0.y*qm+2.f*Dv[1]+w0.y*qp;
    g1[2]=u0.z*qm+2.f*Dv[2]+w0.z*qp; g1[3]=u0.w*qm+2.f*Dv[3]+w0.w*qp;
    g1[4]=u1.x*qm+2.f*Dv[4]+w1.x*qp; g1[5]=u1.y*qm+2.f*Dv[5]+w1.y*qp;
    g1[6]=u1.z*qm+2.f*Dv[6]+w1.z*qp; g1[7]=u1.w*qm+2.f*Dv[7]+w1.w*qp;
    // E: s_z
    u0 = *(const float4*)&S[wid][4][zm][0]; u1 = *(const float4*)&S[wid][4][zm][4];
    w0 = *(const float4*)&S[wid][4][zp][0]; w1 = *(const float4*)&S[wid][4][zp][4];
    g2[0]=u0.x*qm+2.f*Ev[0]+w0.x*qp; g2[1]=u0.y*qm+2.f*Ev[1]+w0.y*qp;
    g2[2]=u0.z*qm+2.f*Ev[2]+w0.z*qp; g2[3]=u0.w*qm+2.f*Ev[3]+w0.w*qp;
    g2[4]=u1.x*qm+2.f*Ev[4]+w1.x*qp; g2[5]=u1.y*qm+2.f*Ev[5]+w1.y*qp;
    g2[6]=u1.z*qm+2.f*Ev[6]+w1.z*qp; g2[7]=u1.w*qm+2.f*Ev[7]+w1.w*qp;
  }
  { uint4 o = { pk2(__sinf(g0[0]),__sinf(g0[1])), pk2(__sinf(g0[2]),__sinf(g0[3])),
                pk2(__sinf(g0[4]),__sinf(g0[5])), pk2(__sinf(g0[6]),__sinf(g0[7])) };
    *(uint4*)(feat + fb + (size_t)C_*L_) = o; }
  { uint4 o = { pk2(__sinf(g1[0]),__sinf(g1[1])), pk2(__sinf(g1[2]),__sinf(g1[3])),
                pk2(__sinf(g1[4]),__sinf(g1[5])), pk2(__sinf(g1[6]),__sinf(g1[7])) };
    *(uint4*)(feat + fb + (size_t)2*C_*L_) = o; }
  { uint4 o = { pk2(__sinf(g2[0]),__sinf(g2[1])), pk2(__sinf(g2[2]),__sinf(g2[3])),
                pk2(__sinf(g2[4]),__sinf(g2[5])), pk2(__sinf(g2[6]),__sinf(g2[7])) };
    *(uint4*)(feat + fb + (size_t)3*C_*L_) = o; }
}

// ---------------- dyna: per-sample hypernet GEMMs (MFMA bf16) + x update
// grid (B, 2); 4 waves, wave handles 64 columns. Fused wh/ws k-loop, wl via LDS h_t.
__global__ __launch_bounds__(256) void k_dyna(float* __restrict__ x,
    const unsigned short* __restrict__ feat, const float* __restrict__ p,
    const float* __restrict__ leak){
  int b = blockIdx.x, tid = threadIdx.x;
  int wid = tid >> 6, lane = tid & 63, col = lane & 15, quad = lane >> 4;
  int s0 = blockIdx.y * 256;
  int ncol = s0 + wid*64;
  const float* pb = p + (size_t)b*PT_;
  const unsigned short* fbase = feat + (size_t)b*4*C_*L_;
  __shared__ __attribute__((aligned(16))) unsigned short h_t[256][72]; // [n][f], +8 pad

  f32x4 zz4 = {0.f, 0.f, 0.f, 0.f};
  f32x4 acc_h[16], acc_s[16];
  #pragma unroll
  for (int i = 0; i < 16; i++){ acc_h[i] = zz4; acc_s[i] = zz4; }

  for (int k0 = 0; k0 < 256; k0 += 32){
    bh8 bf[4];
    #pragma unroll
    for (int nt = 0; nt < 4; nt++){
      const unsigned short* src = fbase + (size_t)(k0 + quad*8)*L_ + ncol + nt*16 + col;
      bh8 t;
      #pragma unroll
      for (int j = 0; j < 8; j++) t[j] = (short)src[(size_t)j*L_];
      bf[nt] = t;
    }
    #pragma unroll
    for (int mt = 0; mt < 4; mt++){
      int m = mt*16 + col;
      const float* wa = pb + (size_t)m*256 + k0 + quad*8;
      const float* wb = pb + OFF_WS + (size_t)m*256 + k0 + quad*8;
      bh8 ah = cvt8(*(const float4*)wa, *(const float4*)(wa+4));
      bh8 aw = cvt8(*(const float4*)wb, *(const float4*)(wb+4));
      #pragma unroll
      for (int nt = 0; nt < 4; nt++){
        acc_h[mt*4+nt] = __builtin_amdgcn_mfma_f32_16x16x32_bf16(ah, bf[nt], acc_h[mt*4+nt], 0, 0, 0);
        acc_s[mt*4+nt] = __builtin_amdgcn_mfma_f32_16x16x32_bf16(aw, bf[nt], acc_s[mt*4+nt], 0, 0, 0);
      }
    }
  }
  // h = leaky(acc_h + bh) -> h_t (transposed, bf16)
  #pragma unroll
  for (int mt = 0; mt < 4; mt++){
    int f0 = mt*16 + quad*4;
    float bh0 = pb[OFF_BH+f0], bh1 = pb[OFF_BH+f0+1], bh2 = pb[OFF_BH+f0+2], bh3 = pb[OFF_BH+f0+3];
    #pragma unroll
    for (int nt = 0; nt < 4; nt++){
      int n = wid*64 + nt*16 + col;
      f32x4 a = acc_h[mt*4+nt];
      uint2 o = { pk2(lrelu(a[0]+bh0), lrelu(a[1]+bh1)),
                  pk2(lrelu(a[2]+bh2), lrelu(a[3]+bh3)) };
      *(uint2*)&h_t[n][f0] = o;
    }
  }
  __syncthreads();
  // phase 2: acc2 = wl @ h
  f32x4 acc2[16];
  #pragma unroll
  for (int i = 0; i < 16; i++) acc2[i] = zz4;
  #pragma unroll
  for (int k0 = 0; k0 < 64; k0 += 32){
    bh8 hb[4];
    #pragma unroll
    for (int nt = 0; nt < 4; nt++){
      int n = wid*64 + nt*16 + col;
      hb[nt] = *(const bh8*)&h_t[n][k0 + quad*8];
    }
    #pragma unroll
    for (int mt = 0; mt < 4; mt++){
      const float* wa = pb + OFF_WL + (size_t)(mt*16 + col)*64 + k0 + quad*8;
      bh8 al = cvt8(*(const float4*)wa, *(const float4*)(wa+4));
      #pragma unroll
      for (int nt = 0; nt < 4; nt++)
        acc2[mt*4+nt] = __builtin_amdgcn_mfma_f32_16x16x32_bf16(al, hb[nt], acc2[mt*4+nt], 0, 0, 0);
    }
  }
  float lk = fminf(fmaxf(leak[0], 0.001f), 1000.f);
  #pragma unroll
  for (int mt = 0; mt < 4; mt++){
    int f0 = mt*16 + quad*4;
    float bs0 = pb[OFF_BS+f0], bs1 = pb[OFF_BS+f0+1], bs2 = pb[OFF_BS+f0+2], bs3 = pb[OFF_BS+f0+3];
    float bl0 = pb[OFF_BL+f0], bl1 = pb[OFF_BL+f0+1], bl2 = pb[OFF_BL+f0+2], bl3 = pb[OFF_BL+f0+3];
    #pragma unroll
    for (int nt = 0; nt < 4; nt++){
      int s = ncol + nt*16 + col;
      f32x4 xs = acc_s[mt*4+nt], dx = acc2[mt*4+nt];
      float ov0 = xs[0] + bs0 + 0.1f*(dx[0] + bl0);
      float ov1 = xs[1] + bs1 + 0.1f*(dx[1] + bl1);
      float ov2 = xs[2] + bs2 + 0.1f*(dx[2] + bl2);
      float ov3 = xs[3] + bs3 + 0.1f*(dx[3] + bl3);
      size_t xi = ((size_t)b*C_ + f0)*L_ + s;
      x[xi]          += lk*ov0;
      x[xi + L_]     += lk*ov1;
      x[xi + 2*L_]   += lk*ov2;
      x[xi + 3*L_]   += lk*ov3;
    }
  }
}

// ---------------- out res1d part 1: t1 = conv3(leaky(x), out_w0) + out_b0
__global__ __launch_bounds__(512) void k_conv_out1(const float* __restrict__ x,
    const float* __restrict__ w, const float* __restrict__ bias, float* __restrict__ t1){
  int b = blockIdx.x, c0 = blockIdx.y * 8, l = threadIdx.x;
  float acc[8];
  #pragma unroll
  for (int j = 0; j < 8; j++) acc[j] = bias[c0+j];
  const float* xb = x + (size_t)b*C_*L_;
  for (int f = 0; f < C_; f++){
    const float* r = xb + f*L_ + l;
    float x0 = (l > 0) ? lrelu(r[-1]) : 0.f;
    float x1 = lrelu(r[0]);
    float x2 = (l < L_-1) ? lrelu(r[1]) : 0.f;
    const float* wb = w + ((size_t)c0*C_ + f)*3;
    #pragma unroll
    for (int j = 0; j < 8; j++){
      const float* wj = wb + (size_t)j*C_*3;
      acc[j] += wj[0]*x0 + wj[1]*x1 + wj[2]*x2;
    }
  }
  #pragma unroll
  for (int j = 0; j < 8; j++) t1[((size_t)b*C_ + c0 + j)*L_ + l] = acc[j];
}

// ---------------- out res1d part 2: x += 0.1*(conv3(leaky(t1), out_w1)+out_b1)
__global__ __launch_bounds__(512) void k_conv_out2(float* __restrict__ x,
    const float* __restrict__ t1, const float* __restrict__ w, const float* __restrict__ bias){
  int b = blockIdx.x, c0 = blockIdx.y * 8, l = threadIdx.x;
  float acc[8];
  #pragma unroll
  for (int j = 0; j < 8; j++) acc[j] = 0.f;
  const float* tb = t1 + (size_t)b*C_*L_;
  for (int f = 0; f < C_; f++){
    const float* r = tb + f*L_ + l;
    float x0 = (l > 0) ? lrelu(r[-1]) : 0.f;
    float x1 = lrelu(r[0]);
    float x2 = (l < L_-1) ? lrelu(r[1]) : 0.f;
    const float* wb = w + ((size_t)c0*C_ + f)*3;
    #pragma unroll
    for (int j = 0; j < 8; j++){
      const float* wj = wb + (size_t)j*C_*3;
      acc[j] += wj[0]*x0 + wj[1]*x1 + wj[2]*x2;
    }
  }
  #pragma unroll
  for (int j = 0; j < 8; j++){
    size_t xi = ((size_t)b*C_ + c0 + j)*L_ + l;
    x[xi] += 0.1f*(bias[c0+j] + acc[j]);
  }
}

// ---------------- loss: cross-entropy vs argmax(codes)
__global__ __launch_bounds__(256) void k_loss(const float* __restrict__ x,
    const float* __restrict__ codes, float* __restrict__ out){
  int b = blockIdx.x;
  int l = blockIdx.y*256 + threadIdx.x;
  const float* xb = x + (size_t)b*C_*L_ + l;
  const float* cb = codes + (size_t)b*C_*L_ + l;
  float m = -1e30f, cm = -1e30f;
  int ci = 0;
  for (int c = 0; c < C_; c++){
    float xv = xb[(size_t)c*L_];
    m = fmaxf(m, xv);
    float cv = cb[(size_t)c*L_];
    if (cv > cm){ cm = cv; ci = c; }
  }
  float s = 0.f, vi = 0.f;
  for (int c = 0; c < C_; c++){
    float xv = xb[(size_t)c*L_];
    s += expf(xv - m);
    if (c == ci) vi = xv;
  }
  float lp = vi - m - logf(s);
  __shared__ float red[256];
  red[threadIdx.x] = -lp; __syncthreads();
  for (int sft = 128; sft; sft >>= 1){
    if (threadIdx.x < sft) red[threadIdx.x] += red[threadIdx.x + sft];
    __syncthreads();
  }
  if (threadIdx.x == 0) atomicAdd(out + B_*L_, red[0] * (1.0f/131072.0f));
}

// ---------------- lat head: l1 res (1x1) + l2 res (1x1) -> out[b][l]
__global__ __launch_bounds__(256) void k_lat(const float* __restrict__ x,
    const float* __restrict__ w10, const float* __restrict__ b10,
    const float* __restrict__ w11, const float* __restrict__ b11,
    const float* __restrict__ w20, const float* __restrict__ b20,
    const float* __restrict__ w21, const float* __restrict__ b21,
    const float* __restrict__ ws2, float* __restrict__ out){
  int b = blockIdx.x, l0 = blockIdx.y*64;
  __shared__ float xc[64][65];
  __shared__ float t1[64][65];
  int tid = threadIdx.x;
  for (int idx = tid; idx < 4096; idx += 256){
    int c = idx >> 6, ll = idx & 63;
    xc[c][ll] = x[((size_t)b*C_ + c)*L_ + l0 + ll];
  }
  __syncthreads();
  int ll = tid & 63, fg = tid >> 6;
  float a[16];
  #pragma unroll
  for (int jj = 0; jj < 16; jj++) a[jj] = b10[fg*16 + jj];
  for (int c = 0; c < C_; c++){
    float xv = lrelu(xc[c][ll]);
    #pragma unroll
    for (int jj = 0; jj < 16; jj++) a[jj] += w10[(size_t)(fg*16 + jj)*C_ + c] * xv;
  }
  #pragma unroll
  for (int jj = 0; jj < 16; jj++) t1[fg*16 + jj][ll] = a[jj];
  __syncthreads();
  #pragma unroll
  for (int jj = 0; jj < 16; jj++) a[jj] = b11[fg*16 + jj];
  for (int f = 0; f < C_; f++){
    float tv = lrelu(t1[f][ll]);
    #pragma unroll
    for (int jj = 0; jj < 16; jj++) a[jj] += w11[(size_t)(fg*16 + jj)*C_ + f] * tv;
  }
  __syncthreads();
  #pragma unroll
  for (int jj = 0; jj < 16; jj++){
    int c = fg*16 + jj;
    xc[c][ll] = xc[c][ll] + 0.1f*a[jj];   // lat1
  }
  __syncthreads();
  if (tid < 64){
    float sxs = 0.f, sdx = 0.f;
    for (int c = 0; c < C_; c++){
      float v = xc[c][tid];
      sxs += ws2[c]*v;
      sdx += w20[c]*lrelu(v);
    }
    float tmid = lrelu(sdx + b20[0]);
    float dx2 = w21[0]*tmid + b21[0];
    out[(size_t)b*L_ + l0 + tid] = sxs + 0.1f*dx2;
  }
}

extern "C" void kernel_launch(void* const* d_in, const int* in_sizes, int n_in,
                              void* d_out, int out_size, void* d_ws, size_t ws_size,
                              hipStream_t stream) {
  (void)in_sizes; (void)n_in; (void)out_size; (void)ws_size;
  const float* codes   = (const float*)d_in[0];
  const int*   y       = (const int*)  d_in[1];
  const float* fc_w    = (const float*)d_in[2];
  const float* fc_b    = (const float*)d_in[3];
  const float* in_w0   = (const float*)d_in[4];
  const float* in_b0   = (const float*)d_in[5];
  const float* in_w1   = (const float*)d_in[6];
  const float* in_b1   = (const float*)d_in[7];
  const float* in_wsp  = (const float*)d_in[8];
  const float* leak    = (const float*)d_in[9];
  const float* hyper_w = (const float*)d_in[10];
  const float* hyper_b = (const float*)d_in[11];
  const float* out_w0  = (const float*)d_in[12];
  const float* out_b0  = (const float*)d_in[13];
  const float* out_w1  = (const float*)d_in[14];
  const float* out_b1  = (const float*)d_in[15];
  const float* l1_w0   = (const float*)d_in[16];
  const float* l1_b0   = (const float*)d_in[17];
  const float* l1_w1   = (const float*)d_in[18];
  const float* l1_b1   = (const float*)d_in[19];
  const float* l2_w0   = (const float*)d_in[20];
  const float* l2_b0   = (const float*)d_in[21];
  const float* l2_w1   = (const float*)d_in[22];
  const float* l2_b1   = (const float*)d_in[23];
  const float* l2_ws   = (const float*)d_in[24];
  float* out = (float*)d_out;

  char* ws = (char*)d_ws;
  float* p             = (float*)(ws);                       // 256*37056*4 = 37,947,392
  float* yembT         = (float*)(ws + 37947392);            // 256*256*4   =    262,144
  float* x             = (float*)(ws + 38209536);            // 256*64*512*4= 33,554,432
  unsigned short* feat = (unsigned short*)(ws + 71763968);   // 256*256*512*2 = 67,108,864
  float* t1            = (float*)(ws + 71763968);            // alias (conv temp, outside loop)

  k_yemb<<<B_, 256, 0, stream>>>(fc_w, fc_b, y, yembT, out);
  k_hyper<<<PT_/16, 256, 0, stream>>>(hyper_w, hyper_b, yembT, p);
  k_conv_in1<<<dim3(B_, 8), 512, 0, stream>>>(codes, in_w0, in_b0, t1);
  k_conv_in2<<<dim3(B_, 8), 512, 0, stream>>>(codes, in_wsp, in_w1, in_b1, t1, x);
  for (int it = 0; it < 8; ++it){
    k_feat<<<B_*C_/4, 256, 0, stream>>>(x, feat);
    k_dyna<<<dim3(B_, 2), 256, 0, stream>>>(x, feat, p, leak);
  }
  k_conv_out1<<<dim3(B_, 8), 512, 0, stream>>>(x, out_w0, out_b0, t1);
  k_conv_out2<<<dim3(B_, 8), 512, 0, stream>>>(x, t1, out_w1, out_b1);
  k_loss<<<dim3(B_, 2), 256, 0, stream>>>(x, codes, out);
  k_lat<<<dim3(B_, 8), 256, 0, stream>>>(x, l1_w0, l1_b0, l1_w1, l1_b1,
                                         l2_w0, l2_b0, l2_w1, l2_b1, l2_ws, out);
}

// Round 3
// 1338.690 us; speedup vs baseline: 1.2521x; 1.2521x over previous
//
#include <hip/hip_runtime.h>

#define B_ 256
#define C_ 64
#define L_ 512
#define CIN_ 82
#define NFREQ_ 9
#define EMB_ 256
#define NLAB_ 10
#define PT_ 37056
#define OFF_BH 16384
#define OFF_WL 16448
#define OFF_BL 20544
#define OFF_WS 20608
#define OFF_BS 36992
#define PI_F 3.14159265358979323846f

typedef short bh8 __attribute__((ext_vector_type(8)));   // 8 bf16 (raw bits)
typedef float f32x4 __attribute__((ext_vector_type(4)));

__device__ inline float lrelu(float v){ return v > 0.f ? v : 0.2f*v; }

__device__ inline unsigned short f2bf(float f){
  unsigned u = __float_as_uint(f);
  u += 0x7FFFu + ((u >> 16) & 1u);      // RNE
  return (unsigned short)(u >> 16);
}
__device__ inline unsigned pk2(float a, float b){
  return (unsigned)f2bf(a) | ((unsigned)f2bf(b) << 16);
}
__device__ inline bh8 cvt8(float4 a, float4 b){
  bh8 r;
  r[0]=(short)f2bf(a.x); r[1]=(short)f2bf(a.y); r[2]=(short)f2bf(a.z); r[3]=(short)f2bf(a.w);
  r[4]=(short)f2bf(b.x); r[5]=(short)f2bf(b.y); r[6]=(short)f2bf(b.z); r[7]=(short)f2bf(b.w);
  return r;
}

// ---------------- yemb: normalize(fc_w[:,y]+fc_b) -> bf16 [b][e]; zero loss slot
__global__ __launch_bounds__(256) void k_yemb(const float* __restrict__ fc_w,
    const float* __restrict__ fc_b, const int* __restrict__ y,
    unsigned short* __restrict__ ybf, float* __restrict__ out){
  int b = blockIdx.x, e = threadIdx.x;
  int lab = y[b];
  float v = fc_w[e*NLAB_ + lab] + fc_b[e];
  __shared__ float red[256];
  red[e] = v*v; __syncthreads();
  for (int s = 128; s; s >>= 1){ if (e < s) red[e] += red[e+s]; __syncthreads(); }
  float nrm = fmaxf(sqrtf(red[0]), 1e-12f);
  ybf[(size_t)b*EMB_ + e] = f2bf(v / nrm);
  if (b == 0 && e == 0) out[B_*L_] = 0.f;
}

// ---------------- hyper (MFMA): p[b][j] = yemb[b][:] . hw[j][:] + hb[j]
__global__ __launch_bounds__(256) void k_hyper(const float* __restrict__ hw,
    const float* __restrict__ hb, const unsigned short* __restrict__ ybf,
    float* __restrict__ p){
  int tid = threadIdx.x;
  int wid = tid >> 6, lane = tid & 63, col = lane & 15, quad = lane >> 4;
  int j = blockIdx.x*64 + wid*16 + col;
  f32x4 acc[16];
  f32x4 z4 = {0.f,0.f,0.f,0.f};
  #pragma unroll
  for (int i = 0; i < 16; i++) acc[i] = z4;
  for (int k0 = 0; k0 < 256; k0 += 32){
    const float* hp = hw + (size_t)j*EMB_ + k0 + quad*8;
    bh8 bf = cvt8(*(const float4*)hp, *(const float4*)(hp+4));
    #pragma unroll
    for (int mt = 0; mt < 16; mt++){
      bh8 af = *(const bh8*)&ybf[(size_t)(mt*16 + col)*EMB_ + k0 + quad*8];
      acc[mt] = __builtin_amdgcn_mfma_f32_16x16x32_bf16(af, bf, acc[mt], 0, 0, 0);
    }
  }
  float hbv = hb[j];
  #pragma unroll
  for (int mt = 0; mt < 16; mt++){
    int b0 = mt*16 + quad*4;
    #pragma unroll
    for (int r = 0; r < 4; r++)
      p[(size_t)(b0 + r)*PT_ + j] = acc[mt][r] + hbv;
  }
}

// positional encoding value (raw, no leaky)
__device__ inline float pe_raw(int fi, int l){
  if (fi < NFREQ_) return __sinf(PI_F / (float)(1 << fi) * (float)l);
  return __cosf(PI_F / (float)(1 << (fi - NFREQ_)) * (float)l);
}

// ---------------- conv_in1: t1 = conv3(leaky(xcat), in_w0) + in_b0
__global__ __launch_bounds__(512) void k_conv_in1(const float* __restrict__ codes,
    const float* __restrict__ w0, const float* __restrict__ b0, float* __restrict__ t1){
  int b = blockIdx.x, c0 = blockIdx.y * 8, l = threadIdx.x;
  float acc[8];
  #pragma unroll
  for (int j = 0; j < 8; j++) acc[j] = b0[c0+j];
  const float* cb = codes + (size_t)b*C_*L_;
  for (int i = 0; i < CIN_; i++){
    float x0, x1, x2;
    if (i < C_){
      const float* r = cb + i*L_ + l;
      x0 = (l > 0) ? r[-1] : 0.f; x1 = r[0]; x2 = (l < L_-1) ? r[1] : 0.f;
    } else {
      int fi = i - C_;
      x0 = (l > 0) ? pe_raw(fi, l-1) : 0.f;
      x1 = pe_raw(fi, l);
      x2 = (l < L_-1) ? pe_raw(fi, l+1) : 0.f;
    }
    x0 = lrelu(x0); x1 = lrelu(x1); x2 = lrelu(x2);
    const float* w = w0 + ((size_t)c0*CIN_ + i)*3;
    #pragma unroll
    for (int j = 0; j < 8; j++){
      const float* wj = w + (size_t)j*CIN_*3;
      acc[j] += wj[0]*x0 + wj[1]*x1 + wj[2]*x2;
    }
  }
  #pragma unroll
  for (int j = 0; j < 8; j++) t1[((size_t)b*C_ + c0 + j)*L_ + l] = acc[j];
}

// ---------------- conv_in2: x = conv1x1(xcat, in_ws) + 0.1*(conv3(leaky(t1), in_w1)+in_b1)
__global__ __launch_bounds__(512) void k_conv_in2(const float* __restrict__ codes,
    const float* __restrict__ wsw, const float* __restrict__ w1, const float* __restrict__ b1,
    const float* __restrict__ t1, float* __restrict__ x){
  int b = blockIdx.x, c0 = blockIdx.y * 8, l = threadIdx.x;
  float accA[8], accB[8];
  #pragma unroll
  for (int j = 0; j < 8; j++){ accA[j] = 0.f; accB[j] = 0.f; }
  const float* cb = codes + (size_t)b*C_*L_;
  for (int i = 0; i < CIN_; i++){
    float xv = (i < C_) ? cb[i*L_ + l] : pe_raw(i - C_, l);
    #pragma unroll
    for (int j = 0; j < 8; j++) accA[j] += wsw[(size_t)(c0+j)*CIN_ + i] * xv;
  }
  const float* tb = t1 + (size_t)b*C_*L_;
  for (int f = 0; f < C_; f++){
    const float* r = tb + f*L_ + l;
    float x0 = (l > 0) ? lrelu(r[-1]) : 0.f;
    float x1 = lrelu(r[0]);
    float x2 = (l < L_-1) ? lrelu(r[1]) : 0.f;
    const float* w = w1 + ((size_t)c0*C_ + f)*3;
    #pragma unroll
    for (int j = 0; j < 8; j++){
      const float* wj = w + (size_t)j*C_*3;
      accB[j] += wj[0]*x0 + wj[1]*x1 + wj[2]*x2;
    }
  }
  #pragma unroll
  for (int j = 0; j < 8; j++)
    x[((size_t)b*C_ + c0 + j)*L_ + l] = accA[j] + 0.1f*(b1[c0+j] + accB[j]);
}

// ---------------- feat: inst-norm + separable sin-sobel -> bf16 feat[b][256][512]
__global__ __launch_bounds__(256) void k_feat(const float* __restrict__ x,
    unsigned short* __restrict__ feat){
  int wid = threadIdx.x >> 6, lane = threadIdx.x & 63;
  int gi = blockIdx.x*4 + wid;                 // = b*64 + c
  const float* xr = x + (size_t)gi*L_ + lane*8;
  float4 v0 = *(const float4*)xr;
  float4 v1 = *(const float4*)(xr + 4);
  float r[8] = { v0.x, v0.y, v0.z, v0.w, v1.x, v1.y, v1.z, v1.w };
  float s1 = 0.f, s2 = 0.f;
  #pragma unroll
  for (int i = 0; i < 8; i++){ s1 += r[i]; s2 += r[i]*r[i]; }
  for (int m = 32; m; m >>= 1){ s1 += __shfl_xor(s1, m); s2 += __shfl_xor(s2, m); }
  float mean = s1 * (1.f/512.f);
  float rstd = rsqrtf(s2*(1.f/512.f) - mean*mean + 1e-5f);
  float xn[8];
  #pragma unroll
  for (int i = 0; i < 8; i++) xn[i] = (r[i] - mean) * rstd;

  size_t fb = ((size_t)(gi >> 6)*4*C_ + (gi & 63))*L_ + lane*8;
  { uint4 o = { pk2(xn[0],xn[1]), pk2(xn[2],xn[3]), pk2(xn[4],xn[5]), pk2(xn[6],xn[7]) };
    *(uint4*)(feat + fb) = o; }

  __shared__ float S[4][5][64][8];   // per-wave: A,B,C,D,E
  float A[8], Bv[8];
  A[0] = 2.f*xn[0] + xn[1];           Bv[0] = xn[1];
  #pragma unroll
  for (int i = 1; i < 7; i++){ A[i] = xn[i-1] + 2.f*xn[i] + xn[i+1]; Bv[i] = xn[i+1] - xn[i-1]; }
  A[7] = xn[6] + 2.f*xn[7];           Bv[7] = -xn[6];
  { float4 a0 = {A[0],A[1],A[2],A[3]}, a1 = {A[4],A[5],A[6],A[7]};
    float4 b0 = {Bv[0],Bv[1],Bv[2],Bv[3]}, b1 = {Bv[4],Bv[5],Bv[6],Bv[7]};
    *(float4*)&S[wid][0][lane][0] = a0; *(float4*)&S[wid][0][lane][4] = a1;
    *(float4*)&S[wid][1][lane][0] = b0; *(float4*)&S[wid][1][lane][4] = b1; }
  __syncthreads();

  int yy = lane & 7, zz = lane >> 3;
  int lm = (yy > 0) ? lane-1 : lane;  float wm = (yy > 0) ? 1.f : 0.f;
  int lp = (yy < 7) ? lane+1 : lane;  float wp = (yy < 7) ? 1.f : 0.f;
  float Am[8], Ap[8], Bm[8], Bp[8];
  { float4 u0, u1;
    u0 = *(const float4*)&S[wid][0][lm][0]; u1 = *(const float4*)&S[wid][0][lm][4];
    Am[0]=u0.x*wm; Am[1]=u0.y*wm; Am[2]=u0.z*wm; Am[3]=u0.w*wm; Am[4]=u1.x*wm; Am[5]=u1.y*wm; Am[6]=u1.z*wm; Am[7]=u1.w*wm;
    u0 = *(const float4*)&S[wid][0][lp][0]; u1 = *(const float4*)&S[wid][0][lp][4];
    Ap[0]=u0.x*wp; Ap[1]=u0.y*wp; Ap[2]=u0.z*wp; Ap[3]=u0.w*wp; Ap[4]=u1.x*wp; Ap[5]=u1.y*wp; Ap[6]=u1.z*wp; Ap[7]=u1.w*wp;
    u0 = *(const float4*)&S[wid][1][lm][0]; u1 = *(const float4*)&S[wid][1][lm][4];
    Bm[0]=u0.x*wm; Bm[1]=u0.y*wm; Bm[2]=u0.z*wm; Bm[3]=u0.w*wm; Bm[4]=u1.x*wm; Bm[5]=u1.y*wm; Bm[6]=u1.z*wm; Bm[7]=u1.w*wm;
    u0 = *(const float4*)&S[wid][1][lp][0]; u1 = *(const float4*)&S[wid][1][lp][4];
    Bp[0]=u0.x*wp; Bp[1]=u0.y*wp; Bp[2]=u0.z*wp; Bp[3]=u0.w*wp; Bp[4]=u1.x*wp; Bp[5]=u1.y*wp; Bp[6]=u1.z*wp; Bp[7]=u1.w*wp;
  }
  float Cv[8], Dv[8], Ev[8];
  #pragma unroll
  for (int i = 0; i < 8; i++){
    Cv[i] = Am[i] + 2.f*A[i] + Ap[i];
    Dv[i] = Ap[i] - Am[i];
    Ev[i] = Bm[i] + 2.f*Bv[i] + Bp[i];
  }
  { float4 c0={Cv[0],Cv[1],Cv[2],Cv[3]}, c1={Cv[4],Cv[5],Cv[6],Cv[7]};
    float4 d0={Dv[0],Dv[1],Dv[2],Dv[3]}, d1={Dv[4],Dv[5],Dv[6],Dv[7]};
    float4 e0={Ev[0],Ev[1],Ev[2],Ev[3]}, e1={Ev[4],Ev[5],Ev[6],Ev[7]};
    *(float4*)&S[wid][2][lane][0]=c0; *(float4*)&S[wid][2][lane][4]=c1;
    *(float4*)&S[wid][3][lane][0]=d0; *(float4*)&S[wid][3][lane][4]=d1;
    *(float4*)&S[wid][4][lane][0]=e0; *(float4*)&S[wid][4][lane][4]=e1; }
  __syncthreads();

  int zm = (zz > 0) ? lane-8 : lane;  float qm = (zz > 0) ? 1.f : 0.f;
  int zp = (zz < 7) ? lane+8 : lane;  float qp = (zz < 7) ? 1.f : 0.f;
  float g0[8], g1[8], g2[8];
  { float4 u0, u1, w0, w1;
    u0 = *(const float4*)&S[wid][2][zm][0]; u1 = *(const float4*)&S[wid][2][zm][4];
    w0 = *(const float4*)&S[wid][2][zp][0]; w1 = *(const float4*)&S[wid][2][zp][4];
    g0[0]=w0.x*qp-u0.x*qm; g0[1]=w0.y*qp-u0.y*qm; g0[2]=w0.z*qp-u0.z*qm; g0[3]=w0.w*qp-u0.w*qm;
    g0[4]=w1.x*qp-u1.x*qm; g0[5]=w1.y*qp-u1.y*qm; g0[6]=w1.z*qp-u1.z*qm; g0[7]=w1.w*qp-u1.w*qm;
    u0 = *(const float4*)&S[wid][3][zm][0]; u1 = *(const float4*)&S[wid][3][zm][4];
    w0 = *(const float4*)&S[wid][3][zp][0]; w1 = *(const float4*)&S[wid][3][zp][4];
    g1[0]=u0.x*qm+2.f*Dv[0]+w0.x*qp; g1[1]=u0.y*qm+2.f*Dv[1]+w0.y*qp;
    g1[2]=u0.z*qm+2.f*Dv[2]+w0.z*qp; g1[3]=u0.w*qm+2.f*Dv[3]+w0.w*qp;
    g1[4]=u1.x*qm+2.f*Dv[4]+w1.x*qp; g1[5]=u1.y*qm+2.f*Dv[5]+w1.y*qp;
    g1[6]=u1.z*qm+2.f*Dv[6]+w1.z*qp; g1[7]=u1.w*qm+2.f*Dv[7]+w1.w*qp;
    u0 = *(const float4*)&S[wid][4][zm][0]; u1 = *(const float4*)&S[wid][4][zm][4];
    w0 = *(const float4*)&S[wid][4][zp][0]; w1 = *(const float4*)&S[wid][4][zp][4];
    g2[0]=u0.x*qm+2.f*Ev[0]+w0.x*qp; g2[1]=u0.y*qm+2.f*Ev[1]+w0.y*qp;
    g2[2]=u0.z*qm+2.f*Ev[2]+w0.z*qp; g2[3]=u0.w*qm+2.f*Ev[3]+w0.w*qp;
    g2[4]=u1.x*qm+2.f*Ev[4]+w1.x*qp; g2[5]=u1.y*qm+2.f*Ev[5]+w1.y*qp;
    g2[6]=u1.z*qm+2.f*Ev[6]+w1.z*qp; g2[7]=u1.w*qm+2.f*Ev[7]+w1.w*qp;
  }
  { uint4 o = { pk2(__sinf(g0[0]),__sinf(g0[1])), pk2(__sinf(g0[2]),__sinf(g0[3])),
                pk2(__sinf(g0[4]),__sinf(g0[5])), pk2(__sinf(g0[6]),__sinf(g0[7])) };
    *(uint4*)(feat + fb + (size_t)C_*L_) = o; }
  { uint4 o = { pk2(__sinf(g1[0]),__sinf(g1[1])), pk2(__sinf(g1[2]),__sinf(g1[3])),
                pk2(__sinf(g1[4]),__sinf(g1[5])), pk2(__sinf(g1[6]),__sinf(g1[7])) };
    *(uint4*)(feat + fb + (size_t)2*C_*L_) = o; }
  { uint4 o = { pk2(__sinf(g2[0]),__sinf(g2[1])), pk2(__sinf(g2[2]),__sinf(g2[3])),
                pk2(__sinf(g2[4]),__sinf(g2[5])), pk2(__sinf(g2[6]),__sinf(g2[7])) };
    *(uint4*)(feat + fb + (size_t)3*C_*L_) = o; }
}

// ---------------- dyna: per-sample hypernet GEMMs (MFMA bf16) + x update
__global__ __launch_bounds__(256) void k_dyna(float* __restrict__ x,
    const unsigned short* __restrict__ feat, const float* __restrict__ p,
    const float* __restrict__ leak){
  int b = blockIdx.x, tid = threadIdx.x;
  int wid = tid >> 6, lane = tid & 63, col = lane & 15, quad = lane >> 4;
  int s0 = blockIdx.y * 256;
  int ncol = s0 + wid*64;
  const float* pb = p + (size_t)b*PT_;
  const unsigned short* fbase = feat + (size_t)b*4*C_*L_;
  __shared__ __attribute__((aligned(16))) unsigned short h_t[256][72];

  f32x4 zz4 = {0.f, 0.f, 0.f, 0.f};
  f32x4 acc_h[16], acc_s[16];
  #pragma unroll
  for (int i = 0; i < 16; i++){ acc_h[i] = zz4; acc_s[i] = zz4; }

  for (int k0 = 0; k0 < 256; k0 += 32){
    bh8 bf[4];
    #pragma unroll
    for (int nt = 0; nt < 4; nt++){
      const unsigned short* src = fbase + (size_t)(k0 + quad*8)*L_ + ncol + nt*16 + col;
      bh8 t;
      #pragma unroll
      for (int j = 0; j < 8; j++) t[j] = (short)src[(size_t)j*L_];
      bf[nt] = t;
    }
    #pragma unroll
    for (int mt = 0; mt < 4; mt++){
      int m = mt*16 + col;
      const float* wa = pb + (size_t)m*256 + k0 + quad*8;
      const float* wb = pb + OFF_WS + (size_t)m*256 + k0 + quad*8;
      bh8 ah = cvt8(*(const float4*)wa, *(const float4*)(wa+4));
      bh8 aw = cvt8(*(const float4*)wb, *(const float4*)(wb+4));
      #pragma unroll
      for (int nt = 0; nt < 4; nt++){
        acc_h[mt*4+nt] = __builtin_amdgcn_mfma_f32_16x16x32_bf16(ah, bf[nt], acc_h[mt*4+nt], 0, 0, 0);
        acc_s[mt*4+nt] = __builtin_amdgcn_mfma_f32_16x16x32_bf16(aw, bf[nt], acc_s[mt*4+nt], 0, 0, 0);
      }
    }
  }
  #pragma unroll
  for (int mt = 0; mt < 4; mt++){
    int f0 = mt*16 + quad*4;
    float bh0 = pb[OFF_BH+f0], bh1 = pb[OFF_BH+f0+1], bh2 = pb[OFF_BH+f0+2], bh3 = pb[OFF_BH+f0+3];
    #pragma unroll
    for (int nt = 0; nt < 4; nt++){
      int n = wid*64 + nt*16 + col;
      f32x4 a = acc_h[mt*4+nt];
      uint2 o = { pk2(lrelu(a[0]+bh0), lrelu(a[1]+bh1)),
                  pk2(lrelu(a[2]+bh2), lrelu(a[3]+bh3)) };
      *(uint2*)&h_t[n][f0] = o;
    }
  }
  __syncthreads();
  f32x4 acc2[16];
  #pragma unroll
  for (int i = 0; i < 16; i++) acc2[i] = zz4;
  #pragma unroll
  for (int k0 = 0; k0 < 64; k0 += 32){
    bh8 hb[4];
    #pragma unroll
    for (int nt = 0; nt < 4; nt++){
      int n = wid*64 + nt*16 + col;
      hb[nt] = *(const bh8*)&h_t[n][k0 + quad*8];
    }
    #pragma unroll
    for (int mt = 0; mt < 4; mt++){
      const float* wa = pb + OFF_WL + (size_t)(mt*16 + col)*64 + k0 + quad*8;
      bh8 al = cvt8(*(const float4*)wa, *(const float4*)(wa+4));
      #pragma unroll
      for (int nt = 0; nt < 4; nt++)
        acc2[mt*4+nt] = __builtin_amdgcn_mfma_f32_16x16x32_bf16(al, hb[nt], acc2[mt*4+nt], 0, 0, 0);
    }
  }
  float lk = fminf(fmaxf(leak[0], 0.001f), 1000.f);
  #pragma unroll
  for (int mt = 0; mt < 4; mt++){
    int f0 = mt*16 + quad*4;
    float bs0 = pb[OFF_BS+f0], bs1 = pb[OFF_BS+f0+1], bs2 = pb[OFF_BS+f0+2], bs3 = pb[OFF_BS+f0+3];
    float bl0 = pb[OFF_BL+f0], bl1 = pb[OFF_BL+f0+1], bl2 = pb[OFF_BL+f0+2], bl3 = pb[OFF_BL+f0+3];
    #pragma unroll
    for (int nt = 0; nt < 4; nt++){
      int s = ncol + nt*16 + col;
      f32x4 xs = acc_s[mt*4+nt], dx = acc2[mt*4+nt];
      float ov0 = xs[0] + bs0 + 0.1f*(dx[0] + bl0);
      float ov1 = xs[1] + bs1 + 0.1f*(dx[1] + bl1);
      float ov2 = xs[2] + bs2 + 0.1f*(dx[2] + bl2);
      float ov3 = xs[3] + bs3 + 0.1f*(dx[3] + bl3);
      size_t xi = ((size_t)b*C_ + f0)*L_ + s;
      x[xi]          += lk*ov0;
      x[xi + L_]     += lk*ov1;
      x[xi + 2*L_]   += lk*ov2;
      x[xi + 3*L_]   += lk*ov3;
    }
  }
}

// ---------------- out res1d part 1: t1 = conv3(leaky(x), out_w0) + out_b0
__global__ __launch_bounds__(512) void k_conv_out1(const float* __restrict__ x,
    const float* __restrict__ w, const float* __restrict__ bias, float* __restrict__ t1){
  int b = blockIdx.x, c0 = blockIdx.y * 8, l = threadIdx.x;
  float acc[8];
  #pragma unroll
  for (int j = 0; j < 8; j++) acc[j] = bias[c0+j];
  const float* xb = x + (size_t)b*C_*L_;
  for (int f = 0; f < C_; f++){
    const float* r = xb + f*L_ + l;
    float x0 = (l > 0) ? lrelu(r[-1]) : 0.f;
    float x1 = lrelu(r[0]);
    float x2 = (l < L_-1) ? lrelu(r[1]) : 0.f;
    const float* wb = w + ((size_t)c0*C_ + f)*3;
    #pragma unroll
    for (int j = 0; j < 8; j++){
      const float* wj = wb + (size_t)j*C_*3;
      acc[j] += wj[0]*x0 + wj[1]*x1 + wj[2]*x2;
    }
  }
  #pragma unroll
  for (int j = 0; j < 8; j++) t1[((size_t)b*C_ + c0 + j)*L_ + l] = acc[j];
}

// ---------------- out res1d part 2: x += 0.1*(conv3(leaky(t1), out_w1)+out_b1)
__global__ __launch_bounds__(512) void k_conv_out2(float* __restrict__ x,
    const float* __restrict__ t1, const float* __restrict__ w, const float* __restrict__ bias){
  int b = blockIdx.x, c0 = blockIdx.y * 8, l = threadIdx.x;
  float acc[8];
  #pragma unroll
  for (int j = 0; j < 8; j++) acc[j] = 0.f;
  const float* tb = t1 + (size_t)b*C_*L_;
  for (int f = 0; f < C_; f++){
    const float* r = tb + f*L_ + l;
    float x0 = (l > 0) ? lrelu(r[-1]) : 0.f;
    float x1 = lrelu(r[0]);
    float x2 = (l < L_-1) ? lrelu(r[1]) : 0.f;
    const float* wb = w + ((size_t)c0*C_ + f)*3;
    #pragma unroll
    for (int j = 0; j < 8; j++){
      const float* wj = wb + (size_t)j*C_*3;
      acc[j] += wj[0]*x0 + wj[1]*x1 + wj[2]*x2;
    }
  }
  #pragma unroll
  for (int j = 0; j < 8; j++){
    size_t xi = ((size_t)b*C_ + c0 + j)*L_ + l;
    x[xi] += 0.1f*(bias[c0+j] + acc[j]);
  }
}

// ---------------- loss: cross-entropy vs argmax(codes)
__global__ __launch_bounds__(256) void k_loss(const float* __restrict__ x,
    const float* __restrict__ codes, float* __restrict__ out){
  int b = blockIdx.x;
  int l = blockIdx.y*256 + threadIdx.x;
  const float* xb = x + (size_t)b*C_*L_ + l;
  const float* cb = codes + (size_t)b*C_*L_ + l;
  float m = -1e30f, cm = -1e30f;
  int ci = 0;
  for (int c = 0; c < C_; c++){
    float xv = xb[(size_t)c*L_];
    m = fmaxf(m, xv);
    float cv = cb[(size_t)c*L_];
    if (cv > cm){ cm = cv; ci = c; }
  }
  float s = 0.f, vi = 0.f;
  for (int c = 0; c < C_; c++){
    float xv = xb[(size_t)c*L_];
    s += expf(xv - m);
    if (c == ci) vi = xv;
  }
  float lp = vi - m - logf(s);
  __shared__ float red[256];
  red[threadIdx.x] = -lp; __syncthreads();
  for (int sft = 128; sft; sft >>= 1){
    if (threadIdx.x < sft) red[threadIdx.x] += red[threadIdx.x + sft];
    __syncthreads();
  }
  if (threadIdx.x == 0) atomicAdd(out + B_*L_, red[0] * (1.0f/131072.0f));
}

// ---------------- lat head (MFMA): two 64x64 GEMMs per (b, 256-col tile) + lat2 reduce
// grid (B, 2); 4 waves; wave owns 64 cols (4 n-tiles). Skip path (ws2.lat1) stays fp32.
__global__ __launch_bounds__(256) void k_lat(const float* __restrict__ x,
    const float* __restrict__ w10, const float* __restrict__ b10,
    const float* __restrict__ w11, const float* __restrict__ b11,
    const float* __restrict__ w20, const float* __restrict__ b20,
    const float* __restrict__ w21, const float* __restrict__ b21,
    const float* __restrict__ ws2, float* __restrict__ out){
  int b = blockIdx.x, l0 = blockIdx.y*256;
  int tid = threadIdx.x;
  int wid = tid >> 6, lane = tid & 63, col = lane & 15, quad = lane >> 4;
  __shared__ __attribute__((aligned(16))) unsigned short wA[2][64][72];  // bf16 [m][k]
  __shared__ __attribute__((aligned(16))) unsigned short Bt[256][72];    // bf16 [n][k], reused

  // stage weights (w10, w11) as bf16
  for (int i = tid; i < 1024; i += 256){
    int arr = i >> 9, rem = i & 511, row = rem >> 3, seg = rem & 7;
    const float* src = (arr ? w11 : w10) + (size_t)row*C_ + seg*8;
    *(bh8*)&wA[arr][row][seg*8] = cvt8(*(const float4*)src, *(const float4*)(src+4));
  }
  // stage Bt = leaky(x) transposed (n-major)
  for (int i = tid; i < 4096; i += 256){
    int c = i >> 6, seg = i & 63;
    float4 v = *(const float4*)&x[((size_t)b*C_ + c)*L_ + l0 + seg*4];
    Bt[seg*4+0][c] = f2bf(lrelu(v.x));
    Bt[seg*4+1][c] = f2bf(lrelu(v.y));
    Bt[seg*4+2][c] = f2bf(lrelu(v.z));
    Bt[seg*4+3][c] = f2bf(lrelu(v.w));
  }
  __syncthreads();
  // GEMM1: t = w10 @ leaky(x)
  f32x4 z4 = {0.f,0.f,0.f,0.f};
  f32x4 acc1[16];
  #pragma unroll
  for (int i = 0; i < 16; i++) acc1[i] = z4;
  #pragma unroll
  for (int k0 = 0; k0 < 64; k0 += 32){
    bh8 bfr[4];
    #pragma unroll
    for (int nt = 0; nt < 4; nt++)
      bfr[nt] = *(const bh8*)&Bt[wid*64 + nt*16 + col][k0 + quad*8];
    #pragma unroll
    for (int mt = 0; mt < 4; mt++){
      bh8 af = *(const bh8*)&wA[0][mt*16 + col][k0 + quad*8];
      #pragma unroll
      for (int nt = 0; nt < 4; nt++)
        acc1[mt*4+nt] = __builtin_amdgcn_mfma_f32_16x16x32_bf16(af, bfr[nt], acc1[mt*4+nt], 0, 0, 0);
    }
  }
  // h = leaky(t + b10) -> Bt (each wave touches only its own n rows; no barrier needed)
  #pragma unroll
  for (int mt = 0; mt < 4; mt++){
    int f0 = mt*16 + quad*4;
    f32x4 bv = *(const f32x4*)&b10[f0];
    #pragma unroll
    for (int nt = 0; nt < 4; nt++){
      int n = wid*64 + nt*16 + col;
      f32x4 a = acc1[mt*4+nt];
      uint2 o = { pk2(lrelu(a[0]+bv[0]), lrelu(a[1]+bv[1])),
                  pk2(lrelu(a[2]+bv[2]), lrelu(a[3]+bv[3])) };
      *(uint2*)&Bt[n][f0] = o;
    }
  }
  // GEMM2: dx = w11 @ h
  f32x4 acc2[16];
  #pragma unroll
  for (int i = 0; i < 16; i++) acc2[i] = z4;
  #pragma unroll
  for (int k0 = 0; k0 < 64; k0 += 32){
    bh8 bfr[4];
    #pragma unroll
    for (int nt = 0; nt < 4; nt++)
      bfr[nt] = *(const bh8*)&Bt[wid*64 + nt*16 + col][k0 + quad*8];
    #pragma unroll
    for (int mt = 0; mt < 4; mt++){
      bh8 af = *(const bh8*)&wA[1][mt*16 + col][k0 + quad*8];
      #pragma unroll
      for (int nt = 0; nt < 4; nt++)
        acc2[mt*4+nt] = __builtin_amdgcn_mfma_f32_16x16x32_bf16(af, bfr[nt], acc2[mt*4+nt], 0, 0, 0);
    }
  }
  // final: lat1 = x + 0.1*(dx + b11); reduce over c with ws2 (fp32 skip) and w20
  float psA[4] = {0.f,0.f,0.f,0.f}, psB[4] = {0.f,0.f,0.f,0.f};
  #pragma unroll
  for (int mt = 0; mt < 4; mt++){
    int f0 = mt*16 + quad*4;
    f32x4 b11v = *(const f32x4*)&b11[f0];
    f32x4 wsv  = *(const f32x4*)&ws2[f0];
    f32x4 w20v = *(const f32x4*)&w20[f0];
    #pragma unroll
    for (int nt = 0; nt < 4; nt++){
      int lg = l0 + wid*64 + nt*16 + col;
      size_t base = ((size_t)b*C_ + f0)*L_ + lg;
      f32x4 a = acc2[mt*4+nt];
      #pragma unroll
      for (int r = 0; r < 4; r++){
        float xv = x[base + (size_t)r*L_];
        float lat = xv + 0.1f*(a[r] + b11v[r]);
        psA[nt] += wsv[r]*lat;
        psB[nt] += w20v[r]*lrelu(lat);
      }
    }
  }
  #pragma unroll
  for (int nt = 0; nt < 4; nt++){
    psA[nt] += __shfl_xor(psA[nt], 16); psA[nt] += __shfl_xor(psA[nt], 32);
    psB[nt] += __shfl_xor(psB[nt], 16); psB[nt] += __shfl_xor(psB[nt], 32);
  }
  if (quad == 0){
    float b20s = b20[0], w21s = w21[0], b21s = b21[0];
    #pragma unroll
    for (int nt = 0; nt < 4; nt++){
      float dx2 = w21s*lrelu(psB[nt] + b20s) + b21s;
      out[(size_t)b*L_ + l0 + wid*64 + nt*16 + col] = psA[nt] + 0.1f*dx2;
    }
  }
}

extern "C" void kernel_launch(void* const* d_in, const int* in_sizes, int n_in,
                              void* d_out, int out_size, void* d_ws, size_t ws_size,
                              hipStream_t stream) {
  (void)in_sizes; (void)n_in; (void)out_size; (void)ws_size;
  const float* codes   = (const float*)d_in[0];
  const int*   y       = (const int*)  d_in[1];
  const float* fc_w    = (const float*)d_in[2];
  const float* fc_b    = (const float*)d_in[3];
  const float* in_w0   = (const float*)d_in[4];
  const float* in_b0   = (const float*)d_in[5];
  const float* in_w1   = (const float*)d_in[6];
  const float* in_b1   = (const float*)d_in[7];
  const float* in_wsp  = (const float*)d_in[8];
  const float* leak    = (const float*)d_in[9];
  const float* hyper_w = (const float*)d_in[10];
  const float* hyper_b = (const float*)d_in[11];
  const float* out_w0  = (const float*)d_in[12];
  const float* out_b0  = (const float*)d_in[13];
  const float* out_w1  = (const float*)d_in[14];
  const float* out_b1  = (const float*)d_in[15];
  const float* l1_w0   = (const float*)d_in[16];
  const float* l1_b0   = (const float*)d_in[17];
  const float* l1_w1   = (const float*)d_in[18];
  const float* l1_b1   = (const float*)d_in[19];
  const float* l2_w0   = (const float*)d_in[20];
  const float* l2_b0   = (const float*)d_in[21];
  const float* l2_w1   = (const float*)d_in[22];
  const float* l2_b1   = (const float*)d_in[23];
  const float* l2_ws   = (const float*)d_in[24];
  float* out = (float*)d_out;

  char* ws = (char*)d_ws;
  float* p             = (float*)(ws);                       // 37,947,392 B
  unsigned short* ybf  = (unsigned short*)(ws + 37947392);   // 131,072 B
  float* x             = (float*)(ws + 38209536);            // 33,554,432 B
  unsigned short* feat = (unsigned short*)(ws + 71763968);   // 67,108,864 B
  float* t1            = (float*)(ws + 71763968);            // alias (conv temp, outside loop)

  k_yemb<<<B_, 256, 0, stream>>>(fc_w, fc_b, y, ybf, out);
  k_hyper<<<PT_/64, 256, 0, stream>>>(hyper_w, hyper_b, ybf, p);
  k_conv_in1<<<dim3(B_, 8), 512, 0, stream>>>(codes, in_w0, in_b0, t1);
  k_conv_in2<<<dim3(B_, 8), 512, 0, stream>>>(codes, in_wsp, in_w1, in_b1, t1, x);
  for (int it = 0; it < 8; ++it){
    k_feat<<<B_*C_/4, 256, 0, stream>>>(x, feat);
    k_dyna<<<dim3(B_, 2), 256, 0, stream>>>(x, feat, p, leak);
  }
  k_conv_out1<<<dim3(B_, 8), 512, 0, stream>>>(x, out_w0, out_b0, t1);
  k_conv_out2<<<dim3(B_, 8), 512, 0, stream>>>(x, t1, out_w1, out_b1);
  k_loss<<<dim3(B_, 2), 256, 0, stream>>>(x, codes, out);
  k_lat<<<dim3(B_, 2), 256, 0, stream>>>(x, l1_w0, l1_b0, l1_w1, l1_b1,
                                         l2_w0, l2_b0, l2_w1, l2_b1, l2_ws, out);
}

// Round 5
// 916.113 us; speedup vs baseline: 1.8297x; 1.4613x over previous
//
#include <hip/hip_runtime.h>

#define B_ 256
#define C_ 64
#define L_ 512
#define CIN_ 82
#define NFREQ_ 9
#define EMB_ 256
#define NLAB_ 10
#define PT_ 37056
#define OFF_BH 16384
#define OFF_WL 16448
#define OFF_BL 20544
#define OFF_WS 20608
#define OFF_BS 36992
#define PI_F 3.14159265358979323846f

typedef short bh8 __attribute__((ext_vector_type(8)));   // 8 bf16 (raw bits)
typedef float f32x4 __attribute__((ext_vector_type(4)));

__device__ inline float lrelu(float v){ return v > 0.f ? v : 0.2f*v; }

__device__ inline unsigned short f2bf(float f){
  unsigned u = __float_as_uint(f);
  u += 0x7FFFu + ((u >> 16) & 1u);      // RNE
  return (unsigned short)(u >> 16);
}
__device__ inline float bf2f(unsigned short u){
  return __uint_as_float((unsigned)u << 16);
}
__device__ inline unsigned pk2(float a, float b){
  return (unsigned)f2bf(a) | ((unsigned)f2bf(b) << 16);
}
__device__ inline bh8 cvt8(float4 a, float4 b){
  bh8 r;
  r[0]=(short)f2bf(a.x); r[1]=(short)f2bf(a.y); r[2]=(short)f2bf(a.z); r[3]=(short)f2bf(a.w);
  r[4]=(short)f2bf(b.x); r[5]=(short)f2bf(b.y); r[6]=(short)f2bf(b.z); r[7]=(short)f2bf(b.w);
  return r;
}

// ---------------- yemb: normalize(fc_w[:,y]+fc_b) -> bf16 [b][e]; zero loss slot
__global__ __launch_bounds__(256) void k_yemb(const float* __restrict__ fc_w,
    const float* __restrict__ fc_b, const int* __restrict__ y,
    unsigned short* __restrict__ ybf, float* __restrict__ out){
  int b = blockIdx.x, e = threadIdx.x;
  int lab = y[b];
  float v = fc_w[e*NLAB_ + lab] + fc_b[e];
  __shared__ float red[256];
  red[e] = v*v; __syncthreads();
  for (int s = 128; s; s >>= 1){ if (e < s) red[e] += red[e+s]; __syncthreads(); }
  float nrm = fmaxf(sqrtf(red[0]), 1e-12f);
  ybf[(size_t)b*EMB_ + e] = f2bf(v / nrm);
  if (b == 0 && e == 0) out[B_*L_] = 0.f;
}

// ---------------- hyper (MFMA): p_bf[b][j] = bf16(yemb[b][:] . hw[j][:] + hb[j])
__global__ __launch_bounds__(256) void k_hyper(const float* __restrict__ hw,
    const float* __restrict__ hb, const unsigned short* __restrict__ ybf,
    unsigned short* __restrict__ p_bf){
  int tid = threadIdx.x;
  int wid = tid >> 6, lane = tid & 63, col = lane & 15, quad = lane >> 4;
  int j = blockIdx.x*64 + wid*16 + col;
  f32x4 acc[16];
  f32x4 z4 = {0.f,0.f,0.f,0.f};
  #pragma unroll
  for (int i = 0; i < 16; i++) acc[i] = z4;
  for (int k0 = 0; k0 < 256; k0 += 32){
    const float* hp = hw + (size_t)j*EMB_ + k0 + quad*8;
    bh8 bf = cvt8(*(const float4*)hp, *(const float4*)(hp+4));
    #pragma unroll
    for (int mt = 0; mt < 16; mt++){
      bh8 af = *(const bh8*)&ybf[(size_t)(mt*16 + col)*EMB_ + k0 + quad*8];
      acc[mt] = __builtin_amdgcn_mfma_f32_16x16x32_bf16(af, bf, acc[mt], 0, 0, 0);
    }
  }
  float hbv = hb[j];
  #pragma unroll
  for (int mt = 0; mt < 16; mt++){
    int b0 = mt*16 + quad*4;
    #pragma unroll
    for (int r = 0; r < 4; r++)
      p_bf[(size_t)(b0 + r)*PT_ + j] = f2bf(acc[mt][r] + hbv);
  }
}

// positional encoding value (raw)
__device__ inline float pe_raw(int fi, int l){
  if (fi < NFREQ_) return __sinf(PI_F / (float)(1 << fi) * (float)l);
  return __cosf(PI_F / (float)(1 << (fi - NFREQ_)) * (float)l);
}

// ---------------- conv_in1 (MFMA): t1bf[b][l][m] = bf16(lrelu(conv3(leaky(xcat), in_w0)+in_b0))
// grid (B,4): 128-col tiles; wave = 32 cols (nt 0..1). K = 96 (82 padded).
__global__ __launch_bounds__(256) void k_conv_in1(const float* __restrict__ codes,
    const float* __restrict__ w0, const float* __restrict__ b0,
    unsigned short* __restrict__ t1bf){
  int b = blockIdx.x, l0 = blockIdx.y*128, tid = threadIdx.x;
  int wid = tid>>6, lane = tid&63, col = lane&15, quad = lane>>4;
  __shared__ __attribute__((aligned(16))) unsigned short xT[136][96];     // rows: l = l0-4+r
  __shared__ __attribute__((aligned(16))) unsigned short wA[3][64][96];
  for (int i = tid; i < 64*96; i += 256){
    int m = i / 96, cin = i % 96;
    if (cin < CIN_){
      const float* s = w0 + (size_t)m*(CIN_*3) + cin*3;
      wA[0][m][cin] = f2bf(s[0]); wA[1][m][cin] = f2bf(s[1]); wA[2][m][cin] = f2bf(s[2]);
    } else { wA[0][m][cin] = 0; wA[1][m][cin] = 0; wA[2][m][cin] = 0; }
  }
  const float* cb = codes + (size_t)b*C_*L_;
  for (int i = tid; i < 96*34; i += 256){
    int c = i / 34, g = i % 34;
    int lg = l0 - 4 + 4*g;
    #pragma unroll
    for (int r2 = 0; r2 < 4; r2++){
      int l = lg + r2;
      float xv = 0.f;
      if (l >= 0 && l < L_){
        if (c < C_) xv = cb[(size_t)c*L_ + l];
        else if (c < CIN_) xv = pe_raw(c - C_, l);
      }
      xT[4*g + r2][c] = f2bf(lrelu(xv));
    }
  }
  __syncthreads();
  f32x4 z4 = {0.f,0.f,0.f,0.f};
  f32x4 acc[8];
  #pragma unroll
  for (int i = 0; i < 8; i++) acc[i] = z4;
  #pragma unroll
  for (int t = 0; t < 3; t++){
    #pragma unroll
    for (int k0 = 0; k0 < 96; k0 += 32){
      bh8 bfr[2];
      #pragma unroll
      for (int nt = 0; nt < 2; nt++)
        bfr[nt] = *(const bh8*)&xT[wid*32 + nt*16 + col + t + 3][k0 + quad*8];
      #pragma unroll
      for (int mt = 0; mt < 4; mt++){
        bh8 af = *(const bh8*)&wA[t][mt*16 + col][k0 + quad*8];
        #pragma unroll
        for (int nt = 0; nt < 2; nt++)
          acc[mt*2+nt] = __builtin_amdgcn_mfma_f32_16x16x32_bf16(af, bfr[nt], acc[mt*2+nt], 0,0,0);
      }
    }
  }
  #pragma unroll
  for (int mt = 0; mt < 4; mt++){
    int f0 = mt*16 + quad*4;
    float q0 = b0[f0], q1 = b0[f0+1], q2 = b0[f0+2], q3 = b0[f0+3];
    #pragma unroll
    for (int nt = 0; nt < 2; nt++){
      int l = l0 + wid*32 + nt*16 + col;
      f32x4 a = acc[mt*2+nt];
      uint2 o = { pk2(lrelu(a[0]+q0), lrelu(a[1]+q1)),
                  pk2(lrelu(a[2]+q2), lrelu(a[3]+q3)) };
      *(uint2*)&t1bf[((size_t)b*L_ + l)*64 + f0] = o;
    }
  }
}

// ---------------- conv_in2 (MFMA): x = conv1x1(xcat, in_ws) + 0.1*(conv3(leaky(t1), in_w1)+in_b1)
// grid (B,4): 128-col tiles. 1x1 from LDS raw xcat; conv3 B-frags direct from global t1bf.
__global__ __launch_bounds__(256) void k_conv_in2(const float* __restrict__ codes,
    const float* __restrict__ wsp, const float* __restrict__ w1, const float* __restrict__ b1,
    const unsigned short* __restrict__ t1bf, float* __restrict__ x){
  int b = blockIdx.x, l0 = blockIdx.y*128, tid = threadIdx.x;
  int wid = tid>>6, lane = tid&63, col = lane&15, quad = lane>>4;
  __shared__ __attribute__((aligned(16))) unsigned short xT[128][96];     // raw xcat, rows: l = l0+r
  __shared__ __attribute__((aligned(16))) unsigned short wsA[64][96];
  __shared__ __attribute__((aligned(16))) unsigned short w1A[3][64][72];
  for (int i = tid; i < 64*96; i += 256){
    int m = i / 96, cin = i % 96;
    wsA[m][cin] = (cin < CIN_) ? f2bf(wsp[(size_t)m*CIN_ + cin]) : (unsigned short)0;
  }
  for (int i = tid; i < 64*64; i += 256){
    int m = i >> 6, cin = i & 63;
    const float* s = w1 + (size_t)m*192 + cin*3;
    w1A[0][m][cin] = f2bf(s[0]); w1A[1][m][cin] = f2bf(s[1]); w1A[2][m][cin] = f2bf(s[2]);
  }
  const float* cb = codes + (size_t)b*C_*L_;
  for (int i = tid; i < 96*32; i += 256){
    int c = i / 32, g = i % 32;
    int lg = l0 + 4*g;
    #pragma unroll
    for (int r2 = 0; r2 < 4; r2++){
      int l = lg + r2;
      float xv;
      if (c < C_) xv = cb[(size_t)c*L_ + l];
      else if (c < CIN_) xv = pe_raw(c - C_, l);
      else xv = 0.f;
      xT[4*g + r2][c] = f2bf(xv);
    }
  }
  __syncthreads();
  f32x4 z4 = {0.f,0.f,0.f,0.f};
  f32x4 accS[8], accD[8];
  #pragma unroll
  for (int i = 0; i < 8; i++){ accS[i] = z4; accD[i] = z4; }
  // 1x1 over raw xcat, K=96
  #pragma unroll
  for (int k0 = 0; k0 < 96; k0 += 32){
    bh8 bfr[2];
    #pragma unroll
    for (int nt = 0; nt < 2; nt++)
      bfr[nt] = *(const bh8*)&xT[wid*32 + nt*16 + col][k0 + quad*8];
    #pragma unroll
    for (int mt = 0; mt < 4; mt++){
      bh8 af = *(const bh8*)&wsA[mt*16 + col][k0 + quad*8];
      #pragma unroll
      for (int nt = 0; nt < 2; nt++)
        accS[mt*2+nt] = __builtin_amdgcn_mfma_f32_16x16x32_bf16(af, bfr[nt], accS[mt*2+nt], 0,0,0);
    }
  }
  // conv3 over leaky(t1) (already leaky'd in t1bf), K=64, B-frags from global
  bh8 zz8 = {0,0,0,0,0,0,0,0};
  #pragma unroll
  for (int t = 0; t < 3; t++){
    #pragma unroll
    for (int k0 = 0; k0 < 64; k0 += 32){
      bh8 bfr[2];
      #pragma unroll
      for (int nt = 0; nt < 2; nt++){
        int l = l0 + wid*32 + nt*16 + col + t - 1;
        bfr[nt] = (l >= 0 && l < L_)
          ? *(const bh8*)&t1bf[((size_t)b*L_ + l)*64 + k0 + quad*8] : zz8;
      }
      #pragma unroll
      for (int mt = 0; mt < 4; mt++){
        bh8 af = *(const bh8*)&w1A[t][mt*16 + col][k0 + quad*8];
        #pragma unroll
        for (int nt = 0; nt < 2; nt++)
          accD[mt*2+nt] = __builtin_amdgcn_mfma_f32_16x16x32_bf16(af, bfr[nt], accD[mt*2+nt], 0,0,0);
      }
    }
  }
  #pragma unroll
  for (int mt = 0; mt < 4; mt++){
    int f0 = mt*16 + quad*4;
    float q0 = b1[f0], q1 = b1[f0+1], q2 = b1[f0+2], q3 = b1[f0+3];
    #pragma unroll
    for (int nt = 0; nt < 2; nt++){
      int l = l0 + wid*32 + nt*16 + col;
      f32x4 s = accS[mt*2+nt], d = accD[mt*2+nt];
      size_t base = ((size_t)b*C_ + f0)*L_ + l;
      x[base]        = s[0] + 0.1f*(d[0] + q0);
      x[base + L_]   = s[1] + 0.1f*(d[1] + q1);
      x[base + 2*L_] = s[2] + 0.1f*(d[2] + q2);
      x[base + 3*L_] = s[3] + 0.1f*(d[3] + q3);
    }
  }
}

// ---------------- feat: inst-norm + separable sin-sobel -> bf16 feat[b][256][512]
__global__ __launch_bounds__(256) void k_feat(const float* __restrict__ x,
    unsigned short* __restrict__ feat){
  int wid = threadIdx.x >> 6, lane = threadIdx.x & 63;
  int gi = blockIdx.x*4 + wid;                 // = b*64 + c
  const float* xr = x + (size_t)gi*L_ + lane*8;
  float4 v0 = *(const float4*)xr;
  float4 v1 = *(const float4*)(xr + 4);
  float r[8] = { v0.x, v0.y, v0.z, v0.w, v1.x, v1.y, v1.z, v1.w };
  float s1 = 0.f, s2 = 0.f;
  #pragma unroll
  for (int i = 0; i < 8; i++){ s1 += r[i]; s2 += r[i]*r[i]; }
  for (int m = 32; m; m >>= 1){ s1 += __shfl_xor(s1, m); s2 += __shfl_xor(s2, m); }
  float mean = s1 * (1.f/512.f);
  float rstd = rsqrtf(s2*(1.f/512.f) - mean*mean + 1e-5f);
  float xn[8];
  #pragma unroll
  for (int i = 0; i < 8; i++) xn[i] = (r[i] - mean) * rstd;

  size_t fb = ((size_t)(gi >> 6)*4*C_ + (gi & 63))*L_ + lane*8;
  { uint4 o = { pk2(xn[0],xn[1]), pk2(xn[2],xn[3]), pk2(xn[4],xn[5]), pk2(xn[6],xn[7]) };
    *(uint4*)(feat + fb) = o; }

  __shared__ float S[4][5][64][8];   // per-wave: A,B,C,D,E
  float A[8], Bv[8];
  A[0] = 2.f*xn[0] + xn[1];           Bv[0] = xn[1];
  #pragma unroll
  for (int i = 1; i < 7; i++){ A[i] = xn[i-1] + 2.f*xn[i] + xn[i+1]; Bv[i] = xn[i+1] - xn[i-1]; }
  A[7] = xn[6] + 2.f*xn[7];           Bv[7] = -xn[6];
  { float4 a0 = {A[0],A[1],A[2],A[3]}, a1 = {A[4],A[5],A[6],A[7]};
    float4 b0 = {Bv[0],Bv[1],Bv[2],Bv[3]}, b1 = {Bv[4],Bv[5],Bv[6],Bv[7]};
    *(float4*)&S[wid][0][lane][0] = a0; *(float4*)&S[wid][0][lane][4] = a1;
    *(float4*)&S[wid][1][lane][0] = b0; *(float4*)&S[wid][1][lane][4] = b1; }
  __syncthreads();

  int yy = lane & 7, zz = lane >> 3;
  int lm = (yy > 0) ? lane-1 : lane;  float wm = (yy > 0) ? 1.f : 0.f;
  int lp = (yy < 7) ? lane+1 : lane;  float wp = (yy < 7) ? 1.f : 0.f;
  float Am[8], Ap[8], Bm[8], Bp[8];
  { float4 u0, u1;
    u0 = *(const float4*)&S[wid][0][lm][0]; u1 = *(const float4*)&S[wid][0][lm][4];
    Am[0]=u0.x*wm; Am[1]=u0.y*wm; Am[2]=u0.z*wm; Am[3]=u0.w*wm; Am[4]=u1.x*wm; Am[5]=u1.y*wm; Am[6]=u1.z*wm; Am[7]=u1.w*wm;
    u0 = *(const float4*)&S[wid][0][lp][0]; u1 = *(const float4*)&S[wid][0][lp][4];
    Ap[0]=u0.x*wp; Ap[1]=u0.y*wp; Ap[2]=u0.z*wp; Ap[3]=u0.w*wp; Ap[4]=u1.x*wp; Ap[5]=u1.y*wp; Ap[6]=u1.z*wp; Ap[7]=u1.w*wp;
    u0 = *(const float4*)&S[wid][1][lm][0]; u1 = *(const float4*)&S[wid][1][lm][4];
    Bm[0]=u0.x*wm; Bm[1]=u0.y*wm; Bm[2]=u0.z*wm; Bm[3]=u0.w*wm; Bm[4]=u1.x*wm; Bm[5]=u1.y*wm; Bm[6]=u1.z*wm; Bm[7]=u1.w*wm;
    u0 = *(const float4*)&S[wid][1][lp][0]; u1 = *(const float4*)&S[wid][1][lp][4];
    Bp[0]=u0.x*wp; Bp[1]=u0.y*wp; Bp[2]=u0.z*wp; Bp[3]=u0.w*wp; Bp[4]=u1.x*wp; Bp[5]=u1.y*wp; Bp[6]=u1.z*wp; Bp[7]=u1.w*wp;
  }
  float Cv[8], Dv[8], Ev[8];
  #pragma unroll
  for (int i = 0; i < 8; i++){
    Cv[i] = Am[i] + 2.f*A[i] + Ap[i];
    Dv[i] = Ap[i] - Am[i];
    Ev[i] = Bm[i] + 2.f*Bv[i] + Bp[i];
  }
  { float4 c0={Cv[0],Cv[1],Cv[2],Cv[3]}, c1={Cv[4],Cv[5],Cv[6],Cv[7]};
    float4 d0={Dv[0],Dv[1],Dv[2],Dv[3]}, d1={Dv[4],Dv[5],Dv[6],Dv[7]};
    float4 e0={Ev[0],Ev[1],Ev[2],Ev[3]}, e1={Ev[4],Ev[5],Ev[6],Ev[7]};
    *(float4*)&S[wid][2][lane][0]=c0; *(float4*)&S[wid][2][lane][4]=c1;
    *(float4*)&S[wid][3][lane][0]=d0; *(float4*)&S[wid][3][lane][4]=d1;
    *(float4*)&S[wid][4][lane][0]=e0; *(float4*)&S[wid][4][lane][4]=e1; }
  __syncthreads();

  int zm = (zz > 0) ? lane-8 : lane;  float qm = (zz > 0) ? 1.f : 0.f;
  int zp = (zz < 7) ? lane+8 : lane;  float qp = (zz < 7) ? 1.f : 0.f;
  float g0[8], g1[8], g2[8];
  { float4 u0, u1, w0, w1;
    u0 = *(const float4*)&S[wid][2][zm][0]; u1 = *(const float4*)&S[wid][2][zm][4];
    w0 = *(const float4*)&S[wid][2][zp][0]; w1 = *(const float4*)&S[wid][2][zp][4];
    g0[0]=w0.x*qp-u0.x*qm; g0[1]=w0.y*qp-u0.y*qm; g0[2]=w0.z*qp-u0.z*qm; g0[3]=w0.w*qp-u0.w*qm;
    g0[4]=w1.x*qp-u1.x*qm; g0[5]=w1.y*qp-u1.y*qm; g0[6]=w1.z*qp-u1.z*qm; g0[7]=w1.w*qp-u1.w*qm;
    u0 = *(const float4*)&S[wid][3][zm][0]; u1 = *(const float4*)&S[wid][3][zm][4];
    w0 = *(const float4*)&S[wid][3][zp][0]; w1 = *(const float4*)&S[wid][3][zp][4];
    g1[0]=u0.x*qm+2.f*Dv[0]+w0.x*qp; g1[1]=u0.y*qm+2.f*Dv[1]+w0.y*qp;
    g1[2]=u0.z*qm+2.f*Dv[2]+w0.z*qp; g1[3]=u0.w*qm+2.f*Dv[3]+w0.w*qp;
    g1[4]=u1.x*qm+2.f*Dv[4]+w1.x*qp; g1[5]=u1.y*qm+2.f*Dv[5]+w1.y*qp;
    g1[6]=u1.z*qm+2.f*Dv[6]+w1.z*qp; g1[7]=u1.w*qm+2.f*Dv[7]+w1.w*qp;
    u0 = *(const float4*)&S[wid][4][zm][0]; u1 = *(const float4*)&S[wid][4][zm][4];
    w0 = *(const float4*)&S[wid][4][zp][0]; w1 = *(const float4*)&S[wid][4][zp][4];
    g2[0]=u0.x*qm+2.f*Ev[0]+w0.x*qp; g2[1]=u0.y*qm+2.f*Ev[1]+w0.y*qp;
    g2[2]=u0.z*qm+2.f*Ev[2]+w0.z*qp; g2[3]=u0.w*qm+2.f*Ev[3]+w0.w*qp;
    g2[4]=u1.x*qm+2.f*Ev[4]+w1.x*qp; g2[5]=u1.y*qm+2.f*Ev[5]+w1.y*qp;
    g2[6]=u1.z*qm+2.f*Ev[6]+w1.z*qp; g2[7]=u1.w*qm+2.f*Ev[7]+w1.w*qp;
  }
  { uint4 o = { pk2(__sinf(g0[0]),__sinf(g0[1])), pk2(__sinf(g0[2]),__sinf(g0[3])),
                pk2(__sinf(g0[4]),__sinf(g0[5])), pk2(__sinf(g0[6]),__sinf(g0[7])) };
    *(uint4*)(feat + fb + (size_t)C_*L_) = o; }
  { uint4 o = { pk2(__sinf(g1[0]),__sinf(g1[1])), pk2(__sinf(g1[2]),__sinf(g1[3])),
                pk2(__sinf(g1[4]),__sinf(g1[5])), pk2(__sinf(g1[6]),__sinf(g1[7])) };
    *(uint4*)(feat + fb + (size_t)2*C_*L_) = o; }
  { uint4 o = { pk2(__sinf(g2[0]),__sinf(g2[1])), pk2(__sinf(g2[2]),__sinf(g2[3])),
                pk2(__sinf(g2[4]),__sinf(g2[5])), pk2(__sinf(g2[6]),__sinf(g2[7])) };
    *(uint4*)(feat + fb + (size_t)3*C_*L_) = o; }
}

// ---------------- dyna: per-sample hypernet GEMMs (MFMA bf16, p in bf16) + x update
__global__ __launch_bounds__(256) void k_dyna(float* __restrict__ x,
    const unsigned short* __restrict__ feat, const unsigned short* __restrict__ p_bf,
    const float* __restrict__ leak){
  int b = blockIdx.x, tid = threadIdx.x;
  int wid = tid >> 6, lane = tid & 63, col = lane & 15, quad = lane >> 4;
  int s0 = blockIdx.y * 256;
  int ncol = s0 + wid*64;
  const unsigned short* pb = p_bf + (size_t)b*PT_;
  const unsigned short* fbase = feat + (size_t)b*4*C_*L_;
  __shared__ __attribute__((aligned(16))) unsigned short h_t[256][72];

  f32x4 zz4 = {0.f, 0.f, 0.f, 0.f};
  f32x4 acc_h[16], acc_s[16];
  #pragma unroll
  for (int i = 0; i < 16; i++){ acc_h[i] = zz4; acc_s[i] = zz4; }

  for (int k0 = 0; k0 < 256; k0 += 32){
    bh8 bf[4];
    #pragma unroll
    for (int nt = 0; nt < 4; nt++){
      const unsigned short* src = fbase + (size_t)(k0 + quad*8)*L_ + ncol + nt*16 + col;
      bh8 t;
      #pragma unroll
      for (int j = 0; j < 8; j++) t[j] = (short)src[(size_t)j*L_];
      bf[nt] = t;
    }
    #pragma unroll
    for (int mt = 0; mt < 4; mt++){
      int m = mt*16 + col;
      bh8 ah = *(const bh8*)&pb[(size_t)m*256 + k0 + quad*8];
      bh8 aw = *(const bh8*)&pb[OFF_WS + (size_t)m*256 + k0 + quad*8];
      #pragma unroll
      for (int nt = 0; nt < 4; nt++){
        acc_h[mt*4+nt] = __builtin_amdgcn_mfma_f32_16x16x32_bf16(ah, bf[nt], acc_h[mt*4+nt], 0, 0, 0);
        acc_s[mt*4+nt] = __builtin_amdgcn_mfma_f32_16x16x32_bf16(aw, bf[nt], acc_s[mt*4+nt], 0, 0, 0);
      }
    }
  }
  #pragma unroll
  for (int mt = 0; mt < 4; mt++){
    int f0 = mt*16 + quad*4;
    float bh0 = bf2f(pb[OFF_BH+f0]), bh1 = bf2f(pb[OFF_BH+f0+1]);
    float bh2 = bf2f(pb[OFF_BH+f0+2]), bh3 = bf2f(pb[OFF_BH+f0+3]);
    #pragma unroll
    for (int nt = 0; nt < 4; nt++){
      int n = wid*64 + nt*16 + col;
      f32x4 a = acc_h[mt*4+nt];
      uint2 o = { pk2(lrelu(a[0]+bh0), lrelu(a[1]+bh1)),
                  pk2(lrelu(a[2]+bh2), lrelu(a[3]+bh3)) };
      *(uint2*)&h_t[n][f0] = o;
    }
  }
  __syncthreads();
  f32x4 acc2[16];
  #pragma unroll
  for (int i = 0; i < 16; i++) acc2[i] = zz4;
  #pragma unroll
  for (int k0 = 0; k0 < 64; k0 += 32){
    bh8 hb[4];
    #pragma unroll
    for (int nt = 0; nt < 4; nt++){
      int n = wid*64 + nt*16 + col;
      hb[nt] = *(const bh8*)&h_t[n][k0 + quad*8];
    }
    #pragma unroll
    for (int mt = 0; mt < 4; mt++){
      bh8 al = *(const bh8*)&pb[OFF_WL + (size_t)(mt*16 + col)*64 + k0 + quad*8];
      #pragma unroll
      for (int nt = 0; nt < 4; nt++)
        acc2[mt*4+nt] = __builtin_amdgcn_mfma_f32_16x16x32_bf16(al, hb[nt], acc2[mt*4+nt], 0, 0, 0);
    }
  }
  float lk = fminf(fmaxf(leak[0], 0.001f), 1000.f);
  #pragma unroll
  for (int mt = 0; mt < 4; mt++){
    int f0 = mt*16 + quad*4;
    float bs0 = bf2f(pb[OFF_BS+f0]), bs1 = bf2f(pb[OFF_BS+f0+1]);
    float bs2 = bf2f(pb[OFF_BS+f0+2]), bs3 = bf2f(pb[OFF_BS+f0+3]);
    float bl0 = bf2f(pb[OFF_BL+f0]), bl1 = bf2f(pb[OFF_BL+f0+1]);
    float bl2 = bf2f(pb[OFF_BL+f0+2]), bl3 = bf2f(pb[OFF_BL+f0+3]);
    #pragma unroll
    for (int nt = 0; nt < 4; nt++){
      int s = ncol + nt*16 + col;
      f32x4 xs = acc_s[mt*4+nt], dx = acc2[mt*4+nt];
      float ov0 = xs[0] + bs0 + 0.1f*(dx[0] + bl0);
      float ov1 = xs[1] + bs1 + 0.1f*(dx[1] + bl1);
      float ov2 = xs[2] + bs2 + 0.1f*(dx[2] + bl2);
      float ov3 = xs[3] + bs3 + 0.1f*(dx[3] + bl3);
      size_t xi = ((size_t)b*C_ + f0)*L_ + s;
      x[xi]          += lk*ov0;
      x[xi + L_]     += lk*ov1;
      x[xi + 2*L_]   += lk*ov2;
      x[xi + 3*L_]   += lk*ov3;
    }
  }
}

// ---------------- conv_out1 (MFMA): t1bf = bf16(lrelu(conv3(leaky(x), out_w0)+out_b0))
// grid (B,4): 128-col tiles.
__global__ __launch_bounds__(256) void k_conv_out1(const float* __restrict__ x,
    const float* __restrict__ w, const float* __restrict__ bias,
    unsigned short* __restrict__ t1bf){
  int b = blockIdx.x, l0 = blockIdx.y*128, tid = threadIdx.x;
  int wid = tid>>6, lane = tid&63, col = lane&15, quad = lane>>4;
  __shared__ __attribute__((aligned(16))) unsigned short xT[136][72];   // rows: l = l0-4+r
  __shared__ __attribute__((aligned(16))) unsigned short wA[3][64][72];
  for (int i = tid; i < 64*64; i += 256){
    int m = i >> 6, cin = i & 63;
    const float* s = w + (size_t)m*192 + cin*3;
    wA[0][m][cin] = f2bf(s[0]); wA[1][m][cin] = f2bf(s[1]); wA[2][m][cin] = f2bf(s[2]);
  }
  const float* xb = x + (size_t)b*C_*L_;
  for (int i = tid; i < 64*34; i += 256){
    int c = i / 34, g = i % 34;
    int lg = l0 - 4 + 4*g;
    if (lg >= 0 && lg + 3 < L_){
      float4 f = *(const float4*)&xb[(size_t)c*L_ + lg];
      xT[4*g  ][c] = f2bf(lrelu(f.x));
      xT[4*g+1][c] = f2bf(lrelu(f.y));
      xT[4*g+2][c] = f2bf(lrelu(f.z));
      xT[4*g+3][c] = f2bf(lrelu(f.w));
    } else {
      #pragma unroll
      for (int r2 = 0; r2 < 4; r2++){
        int l = lg + r2;
        float v = (l >= 0 && l < L_) ? xb[(size_t)c*L_ + l] : 0.f;
        xT[4*g + r2][c] = f2bf(lrelu(v));
      }
    }
  }
  __syncthreads();
  f32x4 z4 = {0.f,0.f,0.f,0.f};
  f32x4 acc[8];
  #pragma unroll
  for (int i = 0; i < 8; i++) acc[i] = z4;
  #pragma unroll
  for (int t = 0; t < 3; t++){
    #pragma unroll
    for (int k0 = 0; k0 < 64; k0 += 32){
      bh8 bfr[2];
      #pragma unroll
      for (int nt = 0; nt < 2; nt++)
        bfr[nt] = *(const bh8*)&xT[wid*32 + nt*16 + col + t + 3][k0 + quad*8];
      #pragma unroll
      for (int mt = 0; mt < 4; mt++){
        bh8 af = *(const bh8*)&wA[t][mt*16 + col][k0 + quad*8];
        #pragma unroll
        for (int nt = 0; nt < 2; nt++)
          acc[mt*2+nt] = __builtin_amdgcn_mfma_f32_16x16x32_bf16(af, bfr[nt], acc[mt*2+nt], 0,0,0);
      }
    }
  }
  #pragma unroll
  for (int mt = 0; mt < 4; mt++){
    int f0 = mt*16 + quad*4;
    float q0 = bias[f0], q1 = bias[f0+1], q2 = bias[f0+2], q3 = bias[f0+3];
    #pragma unroll
    for (int nt = 0; nt < 2; nt++){
      int l = l0 + wid*32 + nt*16 + col;
      f32x4 a = acc[mt*2+nt];
      uint2 o = { pk2(lrelu(a[0]+q0), lrelu(a[1]+q1)),
                  pk2(lrelu(a[2]+q2), lrelu(a[3]+q3)) };
      *(uint2*)&t1bf[((size_t)b*L_ + l)*64 + f0] = o;
    }
  }
}

// ---------------- conv_out2 (MFMA): x += 0.1*(conv3(leaky(t1), out_w1)+out_b1)
// grid (B,2): 256-col tiles; B-frags direct from global t1bf.
__global__ __launch_bounds__(256) void k_conv_out2(float* __restrict__ x,
    const unsigned short* __restrict__ t1bf, const float* __restrict__ w,
    const float* __restrict__ bias){
  int b = blockIdx.x, l0 = blockIdx.y*256, tid = threadIdx.x;
  int wid = tid>>6, lane = tid&63, col = lane&15, quad = lane>>4;
  __shared__ __attribute__((aligned(16))) unsigned short wA[3][64][72];
  for (int i = tid; i < 64*64; i += 256){
    int m = i >> 6, cin = i & 63;
    const float* s = w + (size_t)m*192 + cin*3;
    wA[0][m][cin] = f2bf(s[0]); wA[1][m][cin] = f2bf(s[1]); wA[2][m][cin] = f2bf(s[2]);
  }
  __syncthreads();
  f32x4 z4 = {0.f,0.f,0.f,0.f};
  f32x4 acc[16];
  #pragma unroll
  for (int i = 0; i < 16; i++) acc[i] = z4;
  bh8 zz8 = {0,0,0,0,0,0,0,0};
  #pragma unroll
  for (int t = 0; t < 3; t++){
    #pragma unroll
    for (int k0 = 0; k0 < 64; k0 += 32){
      bh8 bfr[4];
      #pragma unroll
      for (int nt = 0; nt < 4; nt++){
        int l = l0 + wid*64 + nt*16 + col + t - 1;
        bfr[nt] = (l >= 0 && l < L_)
          ? *(const bh8*)&t1bf[((size_t)b*L_ + l)*64 + k0 + quad*8] : zz8;
      }
      #pragma unroll
      for (int mt = 0; mt < 4; mt++){
        bh8 af = *(const bh8*)&wA[t][mt*16 + col][k0 + quad*8];
        #pragma unroll
        for (int nt = 0; nt < 4; nt++)
          acc[mt*4+nt] = __builtin_amdgcn_mfma_f32_16x16x32_bf16(af, bfr[nt], acc[mt*4+nt], 0,0,0);
      }
    }
  }
  #pragma unroll
  for (int mt = 0; mt < 4; mt++){
    int f0 = mt*16 + quad*4;
    float q0 = bias[f0], q1 = bias[f0+1], q2 = bias[f0+2], q3 = bias[f0+3];
    #pragma unroll
    for (int nt = 0; nt < 4; nt++){
      int l = l0 + wid*64 + nt*16 + col;
      f32x4 a = acc[mt*4+nt];
      size_t base = ((size_t)b*C_ + f0)*L_ + l;
      x[base]        += 0.1f*(a[0] + q0);
      x[base + L_]   += 0.1f*(a[1] + q1);
      x[base + 2*L_] += 0.1f*(a[2] + q2);
      x[base + 3*L_] += 0.1f*(a[3] + q3);
    }
  }
}

// ---------------- loss: cross-entropy vs argmax(codes)
__global__ __launch_bounds__(256) void k_loss(const float* __restrict__ x,
    const float* __restrict__ codes, float* __restrict__ out){
  int b = blockIdx.x;
  int l = blockIdx.y*256 + threadIdx.x;
  const float* xb = x + (size_t)b*C_*L_ + l;
  const float* cb = codes + (size_t)b*C_*L_ + l;
  float m = -1e30f, cm = -1e30f;
  int ci = 0;
  for (int c = 0; c < C_; c++){
    float xv = xb[(size_t)c*L_];
    m = fmaxf(m, xv);
    float cv = cb[(size_t)c*L_];
    if (cv > cm){ cm = cv; ci = c; }
  }
  float s = 0.f, vi = 0.f;
  for (int c = 0; c < C_; c++){
    float xv = xb[(size_t)c*L_];
    s += expf(xv - m);
    if (c == ci) vi = xv;
  }
  float lp = vi - m - logf(s);
  __shared__ float red[256];
  red[threadIdx.x] = -lp; __syncthreads();
  for (int sft = 128; sft; sft >>= 1){
    if (threadIdx.x < sft) red[threadIdx.x] += red[threadIdx.x + sft];
    __syncthreads();
  }
  if (threadIdx.x == 0) atomicAdd(out + B_*L_, red[0] * (1.0f/131072.0f));
}

// ---------------- lat head (MFMA): two 64x64 GEMMs per (b, 256-col tile) + lat2 reduce
__global__ __launch_bounds__(256) void k_lat(const float* __restrict__ x,
    const float* __restrict__ w10, const float* __restrict__ b10,
    const float* __restrict__ w11, const float* __restrict__ b11,
    const float* __restrict__ w20, const float* __restrict__ b20,
    const float* __restrict__ w21, const float* __restrict__ b21,
    const float* __restrict__ ws2, float* __restrict__ out){
  int b = blockIdx.x, l0 = blockIdx.y*256;
  int tid = threadIdx.x;
  int wid = tid >> 6, lane = tid & 63, col = lane & 15, quad = lane >> 4;
  __shared__ __attribute__((aligned(16))) unsigned short wA[2][64][72];
  __shared__ __attribute__((aligned(16))) unsigned short Bt[256][72];

  for (int i = tid; i < 1024; i += 256){
    int arr = i >> 9, rem = i & 511, row = rem >> 3, seg = rem & 7;
    const float* src = (arr ? w11 : w10) + (size_t)row*C_ + seg*8;
    *(bh8*)&wA[arr][row][seg*8] = cvt8(*(const float4*)src, *(const float4*)(src+4));
  }
  for (int i = tid; i < 4096; i += 256){
    int c = i >> 6, seg = i & 63;
    float4 v = *(const float4*)&x[((size_t)b*C_ + c)*L_ + l0 + seg*4];
    Bt[seg*4+0][c] = f2bf(lrelu(v.x));
    Bt[seg*4+1][c] = f2bf(lrelu(v.y));
    Bt[seg*4+2][c] = f2bf(lrelu(v.z));
    Bt[seg*4+3][c] = f2bf(lrelu(v.w));
  }
  __syncthreads();
  f32x4 z4 = {0.f,0.f,0.f,0.f};
  f32x4 acc1[16];
  #pragma unroll
  for (int i = 0; i < 16; i++) acc1[i] = z4;
  #pragma unroll
  for (int k0 = 0; k0 < 64; k0 += 32){
    bh8 bfr[4];
    #pragma unroll
    for (int nt = 0; nt < 4; nt++)
      bfr[nt] = *(const bh8*)&Bt[wid*64 + nt*16 + col][k0 + quad*8];
    #pragma unroll
    for (int mt = 0; mt < 4; mt++){
      bh8 af = *(const bh8*)&wA[0][mt*16 + col][k0 + quad*8];
      #pragma unroll
      for (int nt = 0; nt < 4; nt++)
        acc1[mt*4+nt] = __builtin_amdgcn_mfma_f32_16x16x32_bf16(af, bfr[nt], acc1[mt*4+nt], 0, 0, 0);
    }
  }
  #pragma unroll
  for (int mt = 0; mt < 4; mt++){
    int f0 = mt*16 + quad*4;
    f32x4 bv = *(const f32x4*)&b10[f0];
    #pragma unroll
    for (int nt = 0; nt < 4; nt++){
      int n = wid*64 + nt*16 + col;
      f32x4 a = acc1[mt*4+nt];
      uint2 o = { pk2(lrelu(a[0]+bv[0]), lrelu(a[1]+bv[1])),
                  pk2(lrelu(a[2]+bv[2]), lrelu(a[3]+bv[3])) };
      *(uint2*)&Bt[n][f0] = o;
    }
  }
  f32x4 acc2[16];
  #pragma unroll
  for (int i = 0; i < 16; i++) acc2[i] = z4;
  #pragma unroll
  for (int k0 = 0; k0 < 64; k0 += 32){
    bh8 bfr[4];
    #pragma unroll
    for (int nt = 0; nt < 4; nt++)
      bfr[nt] = *(const bh8*)&Bt[wid*64 + nt*16 + col][k0 + quad*8];
    #pragma unroll
    for (int mt = 0; mt < 4; mt++){
      bh8 af = *(const bh8*)&wA[1][mt*16 + col][k0 + quad*8];
      #pragma unroll
      for (int nt = 0; nt < 4; nt++)
        acc2[mt*4+nt] = __builtin_amdgcn_mfma_f32_16x16x32_bf16(af, bfr[nt], acc2[mt*4+nt], 0, 0, 0);
    }
  }
  float psA[4] = {0.f,0.f,0.f,0.f}, psB[4] = {0.f,0.f,0.f,0.f};
  #pragma unroll
  for (int mt = 0; mt < 4; mt++){
    int f0 = mt*16 + quad*4;
    f32x4 b11v = *(const f32x4*)&b11[f0];
    f32x4 wsv  = *(const f32x4*)&ws2[f0];
    f32x4 w20v = *(const f32x4*)&w20[f0];
    #pragma unroll
    for (int nt = 0; nt < 4; nt++){
      int lg = l0 + wid*64 + nt*16 + col;
      size_t base = ((size_t)b*C_ + f0)*L_ + lg;
      f32x4 a = acc2[mt*4+nt];
      #pragma unroll
      for (int r = 0; r < 4; r++){
        float xv = x[base + (size_t)r*L_];
        float lat = xv + 0.1f*(a[r] + b11v[r]);
        psA[nt] += wsv[r]*lat;
        psB[nt] += w20v[r]*lrelu(lat);
      }
    }
  }
  #pragma unroll
  for (int nt = 0; nt < 4; nt++){
    psA[nt] += __shfl_xor(psA[nt], 16); psA[nt] += __shfl_xor(psA[nt], 32);
    psB[nt] += __shfl_xor(psB[nt], 16); psB[nt] += __shfl_xor(psB[nt], 32);
  }
  if (quad == 0){
    float b20s = b20[0], w21s = w21[0], b21s = b21[0];
    #pragma unroll
    for (int nt = 0; nt < 4; nt++){
      float dx2 = w21s*lrelu(psB[nt] + b20s) + b21s;
      out[(size_t)b*L_ + l0 + wid*64 + nt*16 + col] = psA[nt] + 0.1f*dx2;
    }
  }
}

extern "C" void kernel_launch(void* const* d_in, const int* in_sizes, int n_in,
                              void* d_out, int out_size, void* d_ws, size_t ws_size,
                              hipStream_t stream) {
  (void)in_sizes; (void)n_in; (void)out_size; (void)ws_size;
  const float* codes   = (const float*)d_in[0];
  const int*   y       = (const int*)  d_in[1];
  const float* fc_w    = (const float*)d_in[2];
  const float* fc_b    = (const float*)d_in[3];
  const float* in_w0   = (const float*)d_in[4];
  const float* in_b0   = (const float*)d_in[5];
  const float* in_w1   = (const float*)d_in[6];
  const float* in_b1   = (const float*)d_in[7];
  const float* in_wsp  = (const float*)d_in[8];
  const float* leak    = (const float*)d_in[9];
  const float* hyper_w = (const float*)d_in[10];
  const float* hyper_b = (const float*)d_in[11];
  const float* out_w0  = (const float*)d_in[12];
  const float* out_b0  = (const float*)d_in[13];
  const float* out_w1  = (const float*)d_in[14];
  const float* out_b1  = (const float*)d_in[15];
  const float* l1_w0   = (const float*)d_in[16];
  const float* l1_b0   = (const float*)d_in[17];
  const float* l1_w1   = (const float*)d_in[18];
  const float* l1_b1   = (const float*)d_in[19];
  const float* l2_w0   = (const float*)d_in[20];
  const float* l2_b0   = (const float*)d_in[21];
  const float* l2_w1   = (const float*)d_in[22];
  const float* l2_b1   = (const float*)d_in[23];
  const float* l2_ws   = (const float*)d_in[24];
  float* out = (float*)d_out;

  char* ws = (char*)d_ws;
  unsigned short* p_bf = (unsigned short*)(ws);              // 256*37056*2 = 18,972,672
  unsigned short* ybf  = (unsigned short*)(ws + 18972672);   // 131,072
  float* x             = (float*)(ws + 19103744);            // 33,554,432
  unsigned short* feat = (unsigned short*)(ws + 52658176);   // 67,108,864
  unsigned short* t1bf = (unsigned short*)(ws + 52658176);   // alias (used outside loop only)

  k_yemb<<<B_, 256, 0, stream>>>(fc_w, fc_b, y, ybf, out);
  k_hyper<<<PT_/64, 256, 0, stream>>>(hyper_w, hyper_b, ybf, p_bf);
  k_conv_in1<<<dim3(B_, 4), 256, 0, stream>>>(codes, in_w0, in_b0, t1bf);
  k_conv_in2<<<dim3(B_, 4), 256, 0, stream>>>(codes, in_wsp, in_w1, in_b1, t1bf, x);
  for (int it = 0; it < 8; ++it){
    k_feat<<<B_*C_/4, 256, 0, stream>>>(x, feat);
    k_dyna<<<dim3(B_, 2), 256, 0, stream>>>(x, feat, p_bf, leak);
  }
  k_conv_out1<<<dim3(B_, 4), 256, 0, stream>>>(x, out_w0, out_b0, t1bf);
  k_conv_out2<<<dim3(B_, 2), 256, 0, stream>>>(x, t1bf, out_w1, out_b1);
  k_loss<<<dim3(B_, 2), 256, 0, stream>>>(x, codes, out);
  k_lat<<<dim3(B_, 2), 256, 0, stream>>>(x, l1_w0, l1_b0, l1_w1, l1_b1,
                                         l2_w0, l2_b0, l2_w1, l2_b1, l2_ws, out);
}